// Round 3
// baseline (504.566 us; speedup 1.0000x reference)
//
#include <hip/hip_runtime.h>
#include <math.h>

#define N_NODES 10000
#define N_EDGES 160000
#define N_TOT   170000   // edges + self loops
#define NAG     5000
#define HC      1024     // H*C_HID
#define CH      128
#define NEG     0.2f

// ---------------- CSR build ----------------
__global__ __launch_bounds__(256) void hist_kernel(const int* __restrict__ dst,
                                                   int* __restrict__ deg) {
    int e = blockIdx.x * 256 + threadIdx.x;
    if (e < N_EDGES) atomicAdd(&deg[dst[e]], 1);
}

__global__ __launch_bounds__(1024) void scan_kernel(const int* __restrict__ deg,
                                                    int* __restrict__ row_ptr,
                                                    int* __restrict__ cursor) {
    int t = threadIdx.x;
    const int CHK = 10;
    int base = t * CHK;
    int loc[CHK];
    int sum = 0;
    #pragma unroll
    for (int i = 0; i < CHK; i++) {
        int idx = base + i;
        int d = (idx < N_NODES) ? (deg[idx] + 1) : 0;  // +1 = self loop
        loc[i] = sum;
        sum += d;
    }
    __shared__ int part[1024];
    part[t] = sum;
    __syncthreads();
    for (int off = 1; off < 1024; off <<= 1) {
        int v = (t >= off) ? part[t - off] : 0;
        __syncthreads();
        part[t] += v;
        __syncthreads();
    }
    int pre = (t > 0) ? part[t - 1] : 0;
    #pragma unroll
    for (int i = 0; i < CHK; i++) {
        int idx = base + i;
        if (idx < N_NODES) {
            int v = pre + loc[i];
            row_ptr[idx] = v;
            cursor[idx] = v;
        }
    }
    if (t == 1023) row_ptr[N_NODES] = part[1023];
}

__global__ __launch_bounds__(256) void scatter_kernel(const int* __restrict__ src,
                                                      const int* __restrict__ dst,
                                                      int* __restrict__ cursor,
                                                      int* __restrict__ srcs) {
    int e = blockIdx.x * 256 + threadIdx.x;
    if (e < N_EDGES) {
        int p = atomicAdd(&cursor[dst[e]], 1);
        srcs[p] = src[e];
    } else if (e < N_TOT) {
        int i = e - N_EDGES;
        int p = atomicAdd(&cursor[i], 1);
        srcs[p] = i;                           // self loop
    }
}

// ---------------- Fused layer-1: recompute xl1 per edge from x (rank-16) ----------------
// One block per dst. Thread t owns channels c0=4t..4t+3. x rows are 64 B and
// wave-uniform per edge -> scalar loads from L2-resident 640 KB table.
__global__ __launch_bounds__(256) void gat1_fused(const float* __restrict__ x,
                                                  const float* __restrict__ Wl, const float* __restrict__ bl,
                                                  const float* __restrict__ Wr, const float* __restrict__ br,
                                                  const float* __restrict__ att, const float* __restrict__ bias,
                                                  const int* __restrict__ row_ptr,
                                                  const int* __restrict__ srcs,
                                                  float* __restrict__ h_out) {
    int dstn = blockIdx.x;
    int t = threadIdx.x;
    int c0 = t * 4;
    float4 wl[16];
    #pragma unroll
    for (int k = 0; k < 16; k++) wl[k] = *(const float4*)(Wl + k * HC + c0);
    const float4 att4 = *(const float4*)(att + c0);
    const float4 bl4  = *(const float4*)(bl + c0);

    const float* xdp = x + dstn * 16;
    float xd[16];
    #pragma unroll
    for (int k = 0; k < 16; k++) xd[k] = xdp[k];

    // xr4 = x[dst] @ Wr[:, c0..c0+3] + br
    float4 xr4 = *(const float4*)(br + c0);
    #pragma unroll
    for (int k = 0; k < 16; k++) {
        float4 wr = *(const float4*)(Wr + k * HC + c0);
        xr4.x = fmaf(xd[k], wr.x, xr4.x);
        xr4.y = fmaf(xd[k], wr.y, xr4.y);
        xr4.z = fmaf(xd[k], wr.z, xr4.z);
        xr4.w = fmaf(xd[k], wr.w, xr4.w);
    }

    float ax = 0.f, ay = 0.f, az = 0.f, aw = 0.f, l = 0.f;
    int e0 = row_ptr[dstn], e1 = row_ptr[dstn + 1];
    int e = e0;
    for (; e + 2 <= e1; e += 2) {
        int s0 = srcs[e], s1 = srcs[e + 1];
        const float* xs0 = x + s0 * 16;
        const float* xs1 = x + s1 * 16;
        float4 va = bl4, vb = bl4;
        #pragma unroll
        for (int k = 0; k < 16; k++) {
            float x0 = xs0[k], x1 = xs1[k];
            va.x = fmaf(x0, wl[k].x, va.x); vb.x = fmaf(x1, wl[k].x, vb.x);
            va.y = fmaf(x0, wl[k].y, va.y); vb.y = fmaf(x1, wl[k].y, vb.y);
            va.z = fmaf(x0, wl[k].z, va.z); vb.z = fmaf(x1, wl[k].z, vb.z);
            va.w = fmaf(x0, wl[k].w, va.w); vb.w = fmaf(x1, wl[k].w, vb.w);
        }
        float z0, z1, z2, z3;
        z0 = va.x + xr4.x; z0 = fmaxf(z0, NEG * z0);
        z1 = va.y + xr4.y; z1 = fmaxf(z1, NEG * z1);
        z2 = va.z + xr4.z; z2 = fmaxf(z2, NEG * z2);
        z3 = va.w + xr4.w; z3 = fmaxf(z3, NEG * z3);
        float sa = z0 * att4.x + z1 * att4.y + z2 * att4.z + z3 * att4.w;
        z0 = vb.x + xr4.x; z0 = fmaxf(z0, NEG * z0);
        z1 = vb.y + xr4.y; z1 = fmaxf(z1, NEG * z1);
        z2 = vb.z + xr4.z; z2 = fmaxf(z2, NEG * z2);
        z3 = vb.w + xr4.w; z3 = fmaxf(z3, NEG * z3);
        float sb = z0 * att4.x + z1 * att4.y + z2 * att4.z + z3 * att4.w;
        #pragma unroll
        for (int off = 16; off >= 1; off >>= 1) {
            sa += __shfl_xor(sa, off, 64);
            sb += __shfl_xor(sb, off, 64);
        }
        float wa = __expf(sa), wb = __expf(sb);
        l += wa + wb;
        ax = fmaf(wa, va.x, ax); ax = fmaf(wb, vb.x, ax);
        ay = fmaf(wa, va.y, ay); ay = fmaf(wb, vb.y, ay);
        az = fmaf(wa, va.z, az); az = fmaf(wb, vb.z, az);
        aw = fmaf(wa, va.w, aw); aw = fmaf(wb, vb.w, aw);
    }
    for (; e < e1; e++) {
        int s = srcs[e];
        const float* xs = x + s * 16;
        float4 va = bl4;
        #pragma unroll
        for (int k = 0; k < 16; k++) {
            float x0 = xs[k];
            va.x = fmaf(x0, wl[k].x, va.x);
            va.y = fmaf(x0, wl[k].y, va.y);
            va.z = fmaf(x0, wl[k].z, va.z);
            va.w = fmaf(x0, wl[k].w, va.w);
        }
        float z0 = va.x + xr4.x; z0 = fmaxf(z0, NEG * z0);
        float z1 = va.y + xr4.y; z1 = fmaxf(z1, NEG * z1);
        float z2 = va.z + xr4.z; z2 = fmaxf(z2, NEG * z2);
        float z3 = va.w + xr4.w; z3 = fmaxf(z3, NEG * z3);
        float sa = z0 * att4.x + z1 * att4.y + z2 * att4.z + z3 * att4.w;
        #pragma unroll
        for (int off = 16; off >= 1; off >>= 1) sa += __shfl_xor(sa, off, 64);
        float wa = __expf(sa);
        l += wa;
        ax = fmaf(wa, va.x, ax);
        ay = fmaf(wa, va.y, ay);
        az = fmaf(wa, va.z, az);
        aw = fmaf(wa, va.w, aw);
    }
    float inv = 1.f / (l + 1e-16f);
    __shared__ float lds[HC];
    lds[c0] = ax * inv; lds[c0 + 1] = ay * inv; lds[c0 + 2] = az * inv; lds[c0 + 3] = aw * inv;
    __syncthreads();
    if (t < 32) {
        float r[4];
        #pragma unroll
        for (int j = 0; j < 4; j++) {
            int c = t * 4 + j;
            float s = 0.f;
            #pragma unroll
            for (int h = 0; h < 8; h++) s += lds[h * CH + c];
            s = s * 0.125f + bias[c];
            r[j] = fmaxf(s, 0.f);
        }
        *(float4*)(h_out + (size_t)dstn * CH + t * 4) = make_float4(r[0], r[1], r[2], r[3]);
    }
}

// ---------------- Layer-2 GEMM: [N,128] x [128,1024](+bias) -> xl or xr ----------------
// tile 64 rows x 256 cols; thread = 4 rows x 16 cols; a_sh row-major pad 132
// (conflict-free b128 staging; 2-way-multicast b32 reads); double-buffered W loads.
__global__ __launch_bounds__(256) void gemm_l2k(const float* __restrict__ A,
                                                const float* __restrict__ Wl, const float* __restrict__ bl,
                                                const float* __restrict__ Wr, const float* __restrict__ br,
                                                float* __restrict__ xl, float* __restrict__ xr) {
    const int K = 128;
    int rowblk = blockIdx.x * 64;
    bool right = blockIdx.y >= 4;
    const float* W  = right ? Wr : Wl;
    const float* bs = right ? br : bl;
    float* outp     = right ? xr : xl;
    int colbase = (blockIdx.y & 3) * 256;
    int t = threadIdx.x;
    int lane = t & 63;
    int c0 = colbase + (lane & 15) * 16;
    int r0 = (t >> 6) * 16 + (lane >> 4) * 4;

    __shared__ __align__(16) float a_sh[64][132];
    #pragma unroll
    for (int i = 0; i < 8; i++) {
        int idx = t + i * 256;           // 2048 float4s
        int r = idx >> 5;
        int k4 = (idx & 31) * 4;
        int row = rowblk + r;
        float4 v = make_float4(0.f, 0.f, 0.f, 0.f);
        if (row < N_NODES) v = *(const float4*)(A + (size_t)row * K + k4);
        *(float4*)(&a_sh[r][k4]) = v;
    }
    __syncthreads();

    float4 acc[4][4];
    #pragma unroll
    for (int i = 0; i < 4; i++)
        #pragma unroll
        for (int j = 0; j < 4; j++) acc[i][j] = make_float4(0.f, 0.f, 0.f, 0.f);

    float4 w0[4], w1[4];
    float a0[4], a1[4];
    #pragma unroll
    for (int j = 0; j < 4; j++) w0[j] = *(const float4*)(W + c0 + j * 4);
    #pragma unroll
    for (int i = 0; i < 4; i++) a0[i] = a_sh[r0 + i][0];

    for (int k = 0; k < K; k += 2) {
        #pragma unroll
        for (int j = 0; j < 4; j++) w1[j] = *(const float4*)(W + (size_t)(k + 1) * HC + c0 + j * 4);
        #pragma unroll
        for (int i = 0; i < 4; i++) a1[i] = a_sh[r0 + i][k + 1];
        #pragma unroll
        for (int i = 0; i < 4; i++)
            #pragma unroll
            for (int j = 0; j < 4; j++) {
                acc[i][j].x = fmaf(a0[i], w0[j].x, acc[i][j].x);
                acc[i][j].y = fmaf(a0[i], w0[j].y, acc[i][j].y);
                acc[i][j].z = fmaf(a0[i], w0[j].z, acc[i][j].z);
                acc[i][j].w = fmaf(a0[i], w0[j].w, acc[i][j].w);
            }
        if (k + 2 < K) {
            #pragma unroll
            for (int j = 0; j < 4; j++) w0[j] = *(const float4*)(W + (size_t)(k + 2) * HC + c0 + j * 4);
            #pragma unroll
            for (int i = 0; i < 4; i++) a0[i] = a_sh[r0 + i][k + 2];
        }
        #pragma unroll
        for (int i = 0; i < 4; i++)
            #pragma unroll
            for (int j = 0; j < 4; j++) {
                acc[i][j].x = fmaf(a1[i], w1[j].x, acc[i][j].x);
                acc[i][j].y = fmaf(a1[i], w1[j].y, acc[i][j].y);
                acc[i][j].z = fmaf(a1[i], w1[j].z, acc[i][j].z);
                acc[i][j].w = fmaf(a1[i], w1[j].w, acc[i][j].w);
            }
    }

    float4 bb[4];
    #pragma unroll
    for (int j = 0; j < 4; j++) bb[j] = *(const float4*)(bs + c0 + j * 4);
    #pragma unroll
    for (int i = 0; i < 4; i++) {
        int row = rowblk + r0 + i;
        if (row < N_NODES) {
            #pragma unroll
            for (int j = 0; j < 4; j++) {
                float4 o = make_float4(acc[i][j].x + bb[j].x, acc[i][j].y + bb[j].y,
                                       acc[i][j].z + bb[j].z, acc[i][j].w + bb[j].w);
                *(float4*)(outp + (size_t)row * HC + c0 + j * 4) = o;
            }
        }
    }
}

// ---------------- Fused GATv2 layer 2 (one block per dst) + final linear ----------------
__device__ __forceinline__ float edge_partial(const float4 xs, const float4 xr4, const float4 att4) {
    float z0 = xs.x + xr4.x; z0 = fmaxf(z0, NEG * z0);
    float z1 = xs.y + xr4.y; z1 = fmaxf(z1, NEG * z1);
    float z2 = xs.z + xr4.z; z2 = fmaxf(z2, NEG * z2);
    float z3 = xs.w + xr4.w; z3 = fmaxf(z3, NEG * z3);
    return z0 * att4.x + z1 * att4.y + z2 * att4.z + z3 * att4.w;
}

__global__ __launch_bounds__(256) void gat2_kernel(const float* __restrict__ xl,
                                                   const float* __restrict__ xr,
                                                   const float* __restrict__ att,
                                                   const float* __restrict__ bias,
                                                   const int* __restrict__ row_ptr,
                                                   const int* __restrict__ srcs,
                                                   const float* __restrict__ Wlin,
                                                   const float* __restrict__ blin,
                                                   float* __restrict__ out) {
    int dstn = blockIdx.x;
    int t = threadIdx.x;
    int i0 = t * 4;
    const float4 att4 = *(const float4*)(att + i0);
    const float4 xr4  = *(const float4*)(xr + (size_t)dstn * HC + i0);
    float ax = 0.f, ay = 0.f, az = 0.f, aw = 0.f, l = 0.f;
    int e0 = row_ptr[dstn], e1 = row_ptr[dstn + 1];
    int e = e0;
    for (; e + 8 <= e1; e += 8) {
        int s[8];
        #pragma unroll
        for (int i = 0; i < 8; i++) s[i] = srcs[e + i];
        float4 xv[8];
        #pragma unroll
        for (int i = 0; i < 8; i++) xv[i] = *(const float4*)(xl + (size_t)s[i] * HC + i0);
        float v[8];
        #pragma unroll
        for (int i = 0; i < 8; i++) v[i] = edge_partial(xv[i], xr4, att4);
        #pragma unroll
        for (int off = 16; off >= 1; off >>= 1) {
            #pragma unroll
            for (int i = 0; i < 8; i++) v[i] += __shfl_xor(v[i], off, 64);
        }
        #pragma unroll
        for (int i = 0; i < 8; i++) {
            float w = __expf(v[i]);
            l += w;
            ax = fmaf(w, xv[i].x, ax);
            ay = fmaf(w, xv[i].y, ay);
            az = fmaf(w, xv[i].z, az);
            aw = fmaf(w, xv[i].w, aw);
        }
    }
    for (; e < e1; e++) {
        int s = srcs[e];
        float4 xs = *(const float4*)(xl + (size_t)s * HC + i0);
        float v = edge_partial(xs, xr4, att4);
        #pragma unroll
        for (int off = 16; off >= 1; off >>= 1) v += __shfl_xor(v, off, 64);
        float w = __expf(v);
        l += w;
        ax = fmaf(w, xs.x, ax);
        ay = fmaf(w, xs.y, ay);
        az = fmaf(w, xs.z, az);
        aw = fmaf(w, xs.w, aw);
    }
    float inv = 1.f / (l + 1e-16f);
    __shared__ float lds[HC];
    __shared__ float hrow[CH];
    lds[i0] = ax * inv; lds[i0 + 1] = ay * inv; lds[i0 + 2] = az * inv; lds[i0 + 3] = aw * inv;
    __syncthreads();
    if (t < 32) {
        #pragma unroll
        for (int j = 0; j < 4; j++) {
            int c = t * 4 + j;
            float s = 0.f;
            #pragma unroll
            for (int h = 0; h < 8; h++) s += lds[h * CH + c];
            s = s * 0.125f + bias[c];
            hrow[c] = fmaxf(s, 0.f);
        }
    }
    __syncthreads();
    if (dstn < NAG && t < 64) {
        int j = t & 7, part = t >> 3;
        float v = 0.f;
        #pragma unroll
        for (int kk = 0; kk < 16; kk++) {
            int k = part * 16 + kk;
            v = fmaf(hrow[k], Wlin[k * 8 + j], v);
        }
        v += __shfl_xor(v, 8, 64);
        v += __shfl_xor(v, 16, 64);
        v += __shfl_xor(v, 32, 64);
        if (t < 8) out[(size_t)dstn * 8 + t] = v + blin[t];
    }
}

extern "C" void kernel_launch(void* const* d_in, const int* in_sizes, int n_in,
                              void* d_out, int out_size, void* d_ws, size_t ws_size,
                              hipStream_t stream) {
    const float* x    = (const float*)d_in[0];
    const int*   ei   = (const int*)d_in[1];     // [2, E]
    const float* Wl1  = (const float*)d_in[2];
    const float* bl1  = (const float*)d_in[3];
    const float* Wr1  = (const float*)d_in[4];
    const float* br1  = (const float*)d_in[5];
    const float* att1 = (const float*)d_in[6];
    const float* b1   = (const float*)d_in[7];
    const float* Wl2  = (const float*)d_in[8];
    const float* bl2  = (const float*)d_in[9];
    const float* Wr2  = (const float*)d_in[10];
    const float* br2  = (const float*)d_in[11];
    const float* att2 = (const float*)d_in[12];
    const float* b2   = (const float*)d_in[13];
    const float* Wlin = (const float*)d_in[14];
    const float* blin = (const float*)d_in[15];
    float* out = (float*)d_out;

    const int* esrc = ei;
    const int* edst = ei + N_EDGES;

    // workspace layout
    float* xl = (float*)d_ws;                    // N*1024
    float* xr = xl + (size_t)N_NODES * HC;       // N*1024
    float* h1 = xr + (size_t)N_NODES * HC;       // N*128
    int* deg     = (int*)(h1 + (size_t)N_NODES * CH);
    int* row_ptr = deg + N_NODES;                // N+1
    int* cursor  = row_ptr + N_NODES + 16;
    int* srcs    = cursor + N_NODES;             // N_TOT

    hipMemsetAsync(deg, 0, N_NODES * sizeof(int), stream);
    hist_kernel<<<(N_EDGES + 255) / 256, 256, 0, stream>>>(edst, deg);
    scan_kernel<<<1, 1024, 0, stream>>>(deg, row_ptr, cursor);
    scatter_kernel<<<(N_TOT + 255) / 256, 256, 0, stream>>>(esrc, edst, cursor, srcs);

    gat1_fused<<<N_NODES, 256, 0, stream>>>(x, Wl1, bl1, Wr1, br1, att1, b1,
                                            row_ptr, srcs, h1);
    dim3 ggrid((N_NODES + 63) / 64, 8);
    gemm_l2k<<<ggrid, 256, 0, stream>>>(h1, Wl2, bl2, Wr2, br2, xl, xr);
    gat2_kernel<<<N_NODES, 256, 0, stream>>>(xl, xr, att2, b2, row_ptr, srcs,
                                             Wlin, blin, out);
}

// Round 4
// 338.140 us; speedup vs baseline: 1.4922x; 1.4922x over previous
//
#include <hip/hip_runtime.h>
#include <hip/hip_fp16.h>
#include <math.h>

#define N_NODES 10000
#define N_EDGES 160000
#define N_TOT   170000   // edges + self loops
#define NAG     5000
#define HC      1024     // H*C_HID
#define CH      128
#define NEG     0.2f

// ---------------- CSR build ----------------
__global__ __launch_bounds__(256) void hist_kernel(const int* __restrict__ dst,
                                                   int* __restrict__ deg) {
    int e = blockIdx.x * 256 + threadIdx.x;
    if (e < N_EDGES) atomicAdd(&deg[dst[e]], 1);
}

__global__ __launch_bounds__(1024) void scan_kernel(const int* __restrict__ deg,
                                                    int* __restrict__ row_ptr,
                                                    int* __restrict__ cursor) {
    int t = threadIdx.x;
    const int CHK = 10;
    int base = t * CHK;
    int loc[CHK];
    int sum = 0;
    #pragma unroll
    for (int i = 0; i < CHK; i++) {
        int idx = base + i;
        int d = (idx < N_NODES) ? (deg[idx] + 1) : 0;  // +1 = self loop
        loc[i] = sum;
        sum += d;
    }
    __shared__ int part[1024];
    part[t] = sum;
    __syncthreads();
    for (int off = 1; off < 1024; off <<= 1) {
        int v = (t >= off) ? part[t - off] : 0;
        __syncthreads();
        part[t] += v;
        __syncthreads();
    }
    int pre = (t > 0) ? part[t - 1] : 0;
    #pragma unroll
    for (int i = 0; i < CHK; i++) {
        int idx = base + i;
        if (idx < N_NODES) {
            int v = pre + loc[i];
            row_ptr[idx] = v;
            cursor[idx] = v;
        }
    }
    if (t == 1023) row_ptr[N_NODES] = part[1023];
}

__global__ __launch_bounds__(256) void scatter_kernel(const int* __restrict__ src,
                                                      const int* __restrict__ dst,
                                                      int* __restrict__ cursor,
                                                      int* __restrict__ srcs) {
    int e = blockIdx.x * 256 + threadIdx.x;
    if (e < N_EDGES) {
        int p = atomicAdd(&cursor[dst[e]], 1);
        srcs[p] = src[e];
    } else if (e < N_TOT) {
        int i = e - N_EDGES;
        int p = atomicAdd(&cursor[i], 1);
        srcs[p] = i;                           // self loop
    }
}

// ---------------- Tiled GEMM: [N,K] x [K,1024](+bias) -> xl (fp16) or xr (fp32) ----------------
// grid = (ceil(N/64), 8): y<4 -> left (Wl->xl fp16), y>=4 -> right (Wr->xr fp32).
// thread: wave covers 256 cols once (lane*4 cols), 16 rows per wave -> no W duplication.
// a_sh transposed [K][68]; staging via 4x b32 writes, consecutive lanes -> consecutive
// rows -> conflict-free; reads are full-wave b128 broadcasts.
template <int K>
__global__ __launch_bounds__(256) void gemm_xlxr(const float* __restrict__ A,
                                                 const float* __restrict__ Wl, const float* __restrict__ bl,
                                                 const float* __restrict__ Wr, const float* __restrict__ br,
                                                 __half* __restrict__ xl, float* __restrict__ xr) {
    int rowblk = blockIdx.x * 64;
    bool right = blockIdx.y >= 4;
    const float* W  = right ? Wr : Wl;
    const float* bs = right ? br : bl;
    int colbase = (blockIdx.y & 3) * 256;
    int t = threadIdx.x;
    int c0 = colbase + (t & 63) * 4;     // lane -> 4 contiguous cols
    int r0 = (t >> 6) * 16;              // wave -> 16 rows

    __shared__ __align__(16) float a_sh[K][68];
    const int NF4 = 64 * K / 4;
    for (int idx = t; idx < NF4; idx += 256) {
        int r  = idx & 63;
        int k4 = (idx >> 6) << 2;
        int row = rowblk + r;
        float4 v = make_float4(0.f, 0.f, 0.f, 0.f);
        if (row < N_NODES) v = *(const float4*)(A + (size_t)row * K + k4);
        a_sh[k4][r] = v.x; a_sh[k4 + 1][r] = v.y; a_sh[k4 + 2][r] = v.z; a_sh[k4 + 3][r] = v.w;
    }
    __syncthreads();

    float4 acc[16];
    #pragma unroll
    for (int i = 0; i < 16; i++) acc[i] = make_float4(0.f, 0.f, 0.f, 0.f);

    for (int kb = 0; kb < K; kb += 4) {
        float4 w[4];
        #pragma unroll
        for (int u = 0; u < 4; u++) w[u] = *(const float4*)(W + (size_t)(kb + u) * HC + c0);
        #pragma unroll
        for (int u = 0; u < 4; u++) {
            #pragma unroll
            for (int i = 0; i < 4; i++) {
                float4 av = *(const float4*)(&a_sh[kb + u][r0 + i * 4]);
                acc[i * 4 + 0].x = fmaf(av.x, w[u].x, acc[i * 4 + 0].x);
                acc[i * 4 + 0].y = fmaf(av.x, w[u].y, acc[i * 4 + 0].y);
                acc[i * 4 + 0].z = fmaf(av.x, w[u].z, acc[i * 4 + 0].z);
                acc[i * 4 + 0].w = fmaf(av.x, w[u].w, acc[i * 4 + 0].w);
                acc[i * 4 + 1].x = fmaf(av.y, w[u].x, acc[i * 4 + 1].x);
                acc[i * 4 + 1].y = fmaf(av.y, w[u].y, acc[i * 4 + 1].y);
                acc[i * 4 + 1].z = fmaf(av.y, w[u].z, acc[i * 4 + 1].z);
                acc[i * 4 + 1].w = fmaf(av.y, w[u].w, acc[i * 4 + 1].w);
                acc[i * 4 + 2].x = fmaf(av.z, w[u].x, acc[i * 4 + 2].x);
                acc[i * 4 + 2].y = fmaf(av.z, w[u].y, acc[i * 4 + 2].y);
                acc[i * 4 + 2].z = fmaf(av.z, w[u].z, acc[i * 4 + 2].z);
                acc[i * 4 + 2].w = fmaf(av.z, w[u].w, acc[i * 4 + 2].w);
                acc[i * 4 + 3].x = fmaf(av.w, w[u].x, acc[i * 4 + 3].x);
                acc[i * 4 + 3].y = fmaf(av.w, w[u].y, acc[i * 4 + 3].y);
                acc[i * 4 + 3].z = fmaf(av.w, w[u].z, acc[i * 4 + 3].z);
                acc[i * 4 + 3].w = fmaf(av.w, w[u].w, acc[i * 4 + 3].w);
            }
        }
    }

    float4 bb = *(const float4*)(bs + c0);
    #pragma unroll
    for (int rr = 0; rr < 16; rr++) {
        int row = rowblk + r0 + rr;
        if (row < N_NODES) {
            float4 o = make_float4(acc[rr].x + bb.x, acc[rr].y + bb.y,
                                   acc[rr].z + bb.z, acc[rr].w + bb.w);
            if (right) {
                *(float4*)(xr + (size_t)row * HC + c0) = o;
            } else {
                __half2 h01 = __floats2half2_rn(o.x, o.y);
                __half2 h23 = __floats2half2_rn(o.z, o.w);
                float2 st;
                st.x = *(float*)&h01;
                st.y = *(float*)&h23;
                *(float2*)(xl + (size_t)row * HC + c0) = st;
            }
        }
    }
}

// ---------------- Fused GATv2 attention + aggregation (one block per dst) ----------------
__device__ __forceinline__ float4 unpack_h4(float2 raw) {
    __half2 h01 = *(__half2*)&raw.x;
    __half2 h23 = *(__half2*)&raw.y;
    float2 f01 = __half22float2(h01);
    float2 f23 = __half22float2(h23);
    return make_float4(f01.x, f01.y, f23.x, f23.y);
}

__device__ __forceinline__ float edge_partial(const float4 xs, const float4 xr4, const float4 att4) {
    float z0 = xs.x + xr4.x; z0 = fmaxf(z0, NEG * z0);
    float z1 = xs.y + xr4.y; z1 = fmaxf(z1, NEG * z1);
    float z2 = xs.z + xr4.z; z2 = fmaxf(z2, NEG * z2);
    float z3 = xs.w + xr4.w; z3 = fmaxf(z3, NEG * z3);
    return z0 * att4.x + z1 * att4.y + z2 * att4.z + z3 * att4.w;
}

template <int LAYER>
__global__ __launch_bounds__(256) void gat_kernel(const __half* __restrict__ xl,
                                                  const float* __restrict__ xr,
                                                  const float* __restrict__ att,
                                                  const float* __restrict__ bias,
                                                  const int* __restrict__ row_ptr,
                                                  const int* __restrict__ srcs,
                                                  float* __restrict__ h_out,       // LAYER==1
                                                  const float* __restrict__ Wlin,  // LAYER==2
                                                  const float* __restrict__ blin,
                                                  float* __restrict__ out) {
    int dstn = blockIdx.x;
    int t = threadIdx.x;
    int i0 = t * 4;
    const float4 att4 = *(const float4*)(att + i0);
    const float4 xr4  = *(const float4*)(xr + (size_t)dstn * HC + i0);
    float ax = 0.f, ay = 0.f, az = 0.f, aw = 0.f, l = 0.f;
    int e0 = row_ptr[dstn], e1 = row_ptr[dstn + 1];
    int e = e0;
    // unrolled-by-8 pipeline; scores are small (|alpha|<~3) so no max-subtraction
    for (; e + 8 <= e1; e += 8) {
        int s[8];
        #pragma unroll
        for (int i = 0; i < 8; i++) s[i] = srcs[e + i];
        float2 raw[8];
        #pragma unroll
        for (int i = 0; i < 8; i++) raw[i] = *(const float2*)(xl + (size_t)s[i] * HC + i0);
        float4 xv[8];
        #pragma unroll
        for (int i = 0; i < 8; i++) xv[i] = unpack_h4(raw[i]);
        float v[8];
        #pragma unroll
        for (int i = 0; i < 8; i++) v[i] = edge_partial(xv[i], xr4, att4);
        #pragma unroll
        for (int off = 16; off >= 1; off >>= 1) {
            #pragma unroll
            for (int i = 0; i < 8; i++) v[i] += __shfl_xor(v[i], off, 64);
        }
        #pragma unroll
        for (int i = 0; i < 8; i++) {
            float w = __expf(v[i]);
            l += w;
            ax = fmaf(w, xv[i].x, ax);
            ay = fmaf(w, xv[i].y, ay);
            az = fmaf(w, xv[i].z, az);
            aw = fmaf(w, xv[i].w, aw);
        }
    }
    for (; e < e1; e++) {
        int s = srcs[e];
        float4 xs = unpack_h4(*(const float2*)(xl + (size_t)s * HC + i0));
        float v = edge_partial(xs, xr4, att4);
        #pragma unroll
        for (int off = 16; off >= 1; off >>= 1) v += __shfl_xor(v, off, 64);
        float w = __expf(v);
        l += w;
        ax = fmaf(w, xs.x, ax);
        ay = fmaf(w, xs.y, ay);
        az = fmaf(w, xs.z, az);
        aw = fmaf(w, xs.w, aw);
    }
    float inv = 1.f / (l + 1e-16f);
    __shared__ float lds[HC];
    __shared__ float hrow[CH];
    lds[i0] = ax * inv; lds[i0 + 1] = ay * inv; lds[i0 + 2] = az * inv; lds[i0 + 3] = aw * inv;
    __syncthreads();
    if (t < 32) {
        float r[4];
        #pragma unroll
        for (int j = 0; j < 4; j++) {
            int c = t * 4 + j;
            float s = 0.f;
            #pragma unroll
            for (int h = 0; h < 8; h++) s += lds[h * CH + c];
            s = s * 0.125f + bias[c];
            r[j] = fmaxf(s, 0.f);
            hrow[c] = r[j];
        }
        if (LAYER == 1) {
            *(float4*)(h_out + (size_t)dstn * CH + t * 4) = make_float4(r[0], r[1], r[2], r[3]);
        }
    }
    if (LAYER == 2) {
        __syncthreads();
        if (dstn < NAG && t < 64) {
            int j = t & 7, part = t >> 3;
            float v = 0.f;
            #pragma unroll
            for (int kk = 0; kk < 16; kk++) {
                int k = part * 16 + kk;
                v = fmaf(hrow[k], Wlin[k * 8 + j], v);
            }
            v += __shfl_xor(v, 8, 64);
            v += __shfl_xor(v, 16, 64);
            v += __shfl_xor(v, 32, 64);
            if (t < 8) out[(size_t)dstn * 8 + t] = v + blin[t];
        }
    }
}

extern "C" void kernel_launch(void* const* d_in, const int* in_sizes, int n_in,
                              void* d_out, int out_size, void* d_ws, size_t ws_size,
                              hipStream_t stream) {
    const float* x    = (const float*)d_in[0];
    const int*   ei   = (const int*)d_in[1];     // [2, E]
    const float* Wl1  = (const float*)d_in[2];
    const float* bl1  = (const float*)d_in[3];
    const float* Wr1  = (const float*)d_in[4];
    const float* br1  = (const float*)d_in[5];
    const float* att1 = (const float*)d_in[6];
    const float* b1   = (const float*)d_in[7];
    const float* Wl2  = (const float*)d_in[8];
    const float* bl2  = (const float*)d_in[9];
    const float* Wr2  = (const float*)d_in[10];
    const float* br2  = (const float*)d_in[11];
    const float* att2 = (const float*)d_in[12];
    const float* b2   = (const float*)d_in[13];
    const float* Wlin = (const float*)d_in[14];
    const float* blin = (const float*)d_in[15];
    float* out = (float*)d_out;

    const int* esrc = ei;
    const int* edst = ei + N_EDGES;

    // workspace layout
    char* p = (char*)d_ws;
    __half* xlh = (__half*)p;                  p += (size_t)N_NODES * HC * sizeof(__half);
    float*  xr  = (float*)p;                   p += (size_t)N_NODES * HC * sizeof(float);
    float*  h1  = (float*)p;                   p += (size_t)N_NODES * CH * sizeof(float);
    int* deg     = (int*)p;
    int* row_ptr = deg + N_NODES;              // N+1
    int* cursor  = row_ptr + N_NODES + 16;
    int* srcs    = cursor + N_NODES;           // N_TOT

    hipMemsetAsync(deg, 0, N_NODES * sizeof(int), stream);
    hist_kernel<<<(N_EDGES + 255) / 256, 256, 0, stream>>>(edst, deg);
    scan_kernel<<<1, 1024, 0, stream>>>(deg, row_ptr, cursor);
    scatter_kernel<<<(N_TOT + 255) / 256, 256, 0, stream>>>(esrc, edst, cursor, srcs);

    dim3 ggrid((N_NODES + 63) / 64, 8);
    gemm_xlxr<16><<<ggrid, 256, 0, stream>>>(x, Wl1, bl1, Wr1, br1, xlh, xr);
    gat_kernel<1><<<N_NODES, 256, 0, stream>>>(xlh, xr, att1, b1, row_ptr, srcs,
                                               h1, nullptr, nullptr, nullptr);
    gemm_xlxr<128><<<ggrid, 256, 0, stream>>>(h1, Wl2, bl2, Wr2, br2, xlh, xr);
    gat_kernel<2><<<N_NODES, 256, 0, stream>>>(xlh, xr, att2, b2, row_ptr, srcs,
                                               nullptr, Wlin, blin, out);
}

// Round 5
// 320.220 us; speedup vs baseline: 1.5757x; 1.0560x over previous
//
#include <hip/hip_runtime.h>
#include <hip/hip_fp16.h>
#include <math.h>

#define N_NODES 10000
#define N_EDGES 160000
#define N_TOT   170000   // edges + self loops
#define NAG     5000
#define HC      1024     // H*C_HID
#define CH      128
#define NEG     0.2f

// ---------------- CSR build ----------------
__global__ __launch_bounds__(256) void hist_kernel(const int* __restrict__ dst,
                                                   int* __restrict__ deg) {
    int e = blockIdx.x * 256 + threadIdx.x;
    if (e < N_EDGES) atomicAdd(&deg[dst[e]], 1);
}

__global__ __launch_bounds__(1024) void scan_kernel(const int* __restrict__ deg,
                                                    int* __restrict__ row_ptr,
                                                    int* __restrict__ cursor) {
    int t = threadIdx.x;
    const int CHK = 10;
    int base = t * CHK;
    int loc[CHK];
    int sum = 0;
    #pragma unroll
    for (int i = 0; i < CHK; i++) {
        int idx = base + i;
        int d = (idx < N_NODES) ? (deg[idx] + 1) : 0;  // +1 = self loop
        loc[i] = sum;
        sum += d;
    }
    __shared__ int part[1024];
    part[t] = sum;
    __syncthreads();
    for (int off = 1; off < 1024; off <<= 1) {
        int v = (t >= off) ? part[t - off] : 0;
        __syncthreads();
        part[t] += v;
        __syncthreads();
    }
    int pre = (t > 0) ? part[t - 1] : 0;
    #pragma unroll
    for (int i = 0; i < CHK; i++) {
        int idx = base + i;
        if (idx < N_NODES) {
            int v = pre + loc[i];
            row_ptr[idx] = v;
            cursor[idx] = v;
        }
    }
    if (t == 1023) row_ptr[N_NODES] = part[1023];
}

__global__ __launch_bounds__(256) void scatter_kernel(const int* __restrict__ src,
                                                      const int* __restrict__ dst,
                                                      int* __restrict__ cursor,
                                                      int* __restrict__ srcs) {
    int e = blockIdx.x * 256 + threadIdx.x;
    if (e < N_EDGES) {
        int p = atomicAdd(&cursor[dst[e]], 1);
        srcs[p] = src[e];
    } else if (e < N_TOT) {
        int i = e - N_EDGES;
        int p = atomicAdd(&cursor[i], 1);
        srcs[p] = i;                           // self loop
    }
}

// ---------------- Tiled GEMM: [N,K] x [K,1024](+bias) -> xl (fp16) or xr (fp32) ----------------
// grid = (ceil(N/64), 8): y<4 -> left (Wl->xl fp16), y>=4 -> right (Wr->xr fp32).
// Wave covers 256 cols once (lane*4), 16 rows per wave. W loads double-buffered in
// registers (prefetch kb+4 before the 256 FMAs of kb).
template <int K>
__global__ __launch_bounds__(256) void gemm_xlxr(const float* __restrict__ A,
                                                 const float* __restrict__ Wl, const float* __restrict__ bl,
                                                 const float* __restrict__ Wr, const float* __restrict__ br,
                                                 __half* __restrict__ xl, float* __restrict__ xr,
                                                 int rightRowLimit) {
    int rowblk = blockIdx.x * 64;
    bool right = blockIdx.y >= 4;
    if (right && rowblk >= rightRowLimit) return;   // layer-2: xr only needed for drones
    const float* W  = right ? Wr : Wl;
    const float* bs = right ? br : bl;
    int colbase = (blockIdx.y & 3) * 256;
    int t = threadIdx.x;
    int c0 = colbase + (t & 63) * 4;     // lane -> 4 contiguous cols
    int r0 = (t >> 6) * 16;              // wave -> 16 rows

    __shared__ __align__(16) float a_sh[K][68];
    const int NF4 = 64 * K / 4;
    for (int idx = t; idx < NF4; idx += 256) {
        int r  = idx & 63;
        int k4 = (idx >> 6) << 2;
        int row = rowblk + r;
        float4 v = make_float4(0.f, 0.f, 0.f, 0.f);
        if (row < N_NODES) v = *(const float4*)(A + (size_t)row * K + k4);
        a_sh[k4][r] = v.x; a_sh[k4 + 1][r] = v.y; a_sh[k4 + 2][r] = v.z; a_sh[k4 + 3][r] = v.w;
    }
    __syncthreads();

    float4 acc[16];
    #pragma unroll
    for (int i = 0; i < 16; i++) acc[i] = make_float4(0.f, 0.f, 0.f, 0.f);

    const float* Wp = W + c0;
    float4 wc[4], wn[4];
    #pragma unroll
    for (int u = 0; u < 4; u++) wc[u] = *(const float4*)(Wp + (size_t)u * HC);

    for (int kb = 0; kb < K; kb += 4) {
        int kn = (kb + 4 < K) ? kb + 4 : 0;
        #pragma unroll
        for (int u = 0; u < 4; u++) wn[u] = *(const float4*)(Wp + (size_t)(kn + u) * HC);
        #pragma unroll
        for (int u = 0; u < 4; u++) {
            #pragma unroll
            for (int i = 0; i < 4; i++) {
                float4 av = *(const float4*)(&a_sh[kb + u][r0 + i * 4]);
                acc[i * 4 + 0].x = fmaf(av.x, wc[u].x, acc[i * 4 + 0].x);
                acc[i * 4 + 0].y = fmaf(av.x, wc[u].y, acc[i * 4 + 0].y);
                acc[i * 4 + 0].z = fmaf(av.x, wc[u].z, acc[i * 4 + 0].z);
                acc[i * 4 + 0].w = fmaf(av.x, wc[u].w, acc[i * 4 + 0].w);
                acc[i * 4 + 1].x = fmaf(av.y, wc[u].x, acc[i * 4 + 1].x);
                acc[i * 4 + 1].y = fmaf(av.y, wc[u].y, acc[i * 4 + 1].y);
                acc[i * 4 + 1].z = fmaf(av.y, wc[u].z, acc[i * 4 + 1].z);
                acc[i * 4 + 1].w = fmaf(av.y, wc[u].w, acc[i * 4 + 1].w);
                acc[i * 4 + 2].x = fmaf(av.z, wc[u].x, acc[i * 4 + 2].x);
                acc[i * 4 + 2].y = fmaf(av.z, wc[u].y, acc[i * 4 + 2].y);
                acc[i * 4 + 2].z = fmaf(av.z, wc[u].z, acc[i * 4 + 2].z);
                acc[i * 4 + 2].w = fmaf(av.z, wc[u].w, acc[i * 4 + 2].w);
                acc[i * 4 + 3].x = fmaf(av.w, wc[u].x, acc[i * 4 + 3].x);
                acc[i * 4 + 3].y = fmaf(av.w, wc[u].y, acc[i * 4 + 3].y);
                acc[i * 4 + 3].z = fmaf(av.w, wc[u].z, acc[i * 4 + 3].z);
                acc[i * 4 + 3].w = fmaf(av.w, wc[u].w, acc[i * 4 + 3].w);
            }
        }
        #pragma unroll
        for (int u = 0; u < 4; u++) wc[u] = wn[u];
    }

    float4 bb = *(const float4*)(bs + c0);
    #pragma unroll
    for (int rr = 0; rr < 16; rr++) {
        int row = rowblk + r0 + rr;
        if (row < N_NODES) {
            float4 o = make_float4(acc[rr].x + bb.x, acc[rr].y + bb.y,
                                   acc[rr].z + bb.z, acc[rr].w + bb.w);
            if (right) {
                *(float4*)(xr + (size_t)row * HC + c0) = o;
            } else {
                __half2 h01 = __floats2half2_rn(o.x, o.y);
                __half2 h23 = __floats2half2_rn(o.z, o.w);
                float2 st;
                st.x = *(float*)&h01;
                st.y = *(float*)&h23;
                *(float2*)(xl + (size_t)row * HC + c0) = st;
            }
        }
    }
}

// ---------------- Fused GATv2 attention + aggregation ----------------
// Block per dst. Thread t: slot = t>>7 (edge A/B), owns 8 channels c0=(t&127)*8.
// Per step the block processes 2 edges; each thread loads 16 B (dwordx4) of fp16.
// Head = 16-lane group within a wave -> 4-shuffle score reduction.
__device__ __forceinline__ void unpack8(float4 raw, float* f) {
    __half2* hp = (__half2*)&raw;
    #pragma unroll
    for (int j = 0; j < 4; j++) {
        float2 fj = __half22float2(hp[j]);
        f[j * 2] = fj.x;
        f[j * 2 + 1] = fj.y;
    }
}

template <int LAYER>
__global__ __launch_bounds__(256) void gat_kernel(const __half* __restrict__ xl,
                                                  const float* __restrict__ xr,
                                                  const float* __restrict__ att,
                                                  const float* __restrict__ bias,
                                                  const int* __restrict__ row_ptr,
                                                  const int* __restrict__ srcs,
                                                  float* __restrict__ h_out,       // LAYER==1
                                                  const float* __restrict__ Wlin,  // LAYER==2
                                                  const float* __restrict__ blin,
                                                  float* __restrict__ out) {
    int dstn = blockIdx.x;
    int t = threadIdx.x;
    int slot = t >> 7;
    int c0 = (t & 127) * 8;

    float xrv[8], attv[8];
    {
        float4 a0 = *(const float4*)(xr + (size_t)dstn * HC + c0);
        float4 a1 = *(const float4*)(xr + (size_t)dstn * HC + c0 + 4);
        xrv[0] = a0.x; xrv[1] = a0.y; xrv[2] = a0.z; xrv[3] = a0.w;
        xrv[4] = a1.x; xrv[5] = a1.y; xrv[6] = a1.z; xrv[7] = a1.w;
        float4 b0 = *(const float4*)(att + c0);
        float4 b1 = *(const float4*)(att + c0 + 4);
        attv[0] = b0.x; attv[1] = b0.y; attv[2] = b0.z; attv[3] = b0.w;
        attv[4] = b1.x; attv[5] = b1.y; attv[6] = b1.z; attv[7] = b1.w;
    }

    float acc[8];
    #pragma unroll
    for (int j = 0; j < 8; j++) acc[j] = 0.f;
    float lsum = 0.f;

    int e0 = row_ptr[dstn], e1 = row_ptr[dstn + 1];
    int e = e0;
    // main loop: 8 edges per block-step (4 per slot), 4 gathers in flight per wave
    for (; e + 8 <= e1; e += 8) {
        int s[4];
        #pragma unroll
        for (int i = 0; i < 4; i++) s[i] = srcs[e + slot + 2 * i];
        float4 raw[4];
        #pragma unroll
        for (int i = 0; i < 4; i++) raw[i] = *(const float4*)(xl + (size_t)s[i] * HC + c0);
        #pragma unroll
        for (int i = 0; i < 4; i++) {
            float f[8];
            unpack8(raw[i], f);
            float p = 0.f;
            #pragma unroll
            for (int j = 0; j < 8; j++) {
                float z = f[j] + xrv[j];
                z = fmaxf(z, NEG * z);
                p = fmaf(z, attv[j], p);
            }
            p += __shfl_xor(p, 1, 64);
            p += __shfl_xor(p, 2, 64);
            p += __shfl_xor(p, 4, 64);
            p += __shfl_xor(p, 8, 64);
            float w = __expf(p);
            lsum += w;
            #pragma unroll
            for (int j = 0; j < 8; j++) acc[j] = fmaf(w, f[j], acc[j]);
        }
    }
    // tail: stride-2 by slot with validity (block-uniform loop bound)
    for (; e < e1; e += 2) {
        int ee = e + slot;
        bool valid = ee < e1;
        int s = srcs[valid ? ee : e];
        float4 raw = *(const float4*)(xl + (size_t)s * HC + c0);
        float f[8];
        unpack8(raw, f);
        float p = 0.f;
        #pragma unroll
        for (int j = 0; j < 8; j++) {
            float z = f[j] + xrv[j];
            z = fmaxf(z, NEG * z);
            p = fmaf(z, attv[j], p);
        }
        p += __shfl_xor(p, 1, 64);
        p += __shfl_xor(p, 2, 64);
        p += __shfl_xor(p, 4, 64);
        p += __shfl_xor(p, 8, 64);
        float w = valid ? __expf(p) : 0.f;
        lsum += w;
        #pragma unroll
        for (int j = 0; j < 8; j++) acc[j] = fmaf(w, f[j], acc[j]);
    }

    __shared__ float part[2][HC];
    __shared__ float lpart[2][8];
    __shared__ float hrow[CH];
    #pragma unroll
    for (int j = 0; j < 8; j++) part[slot][c0 + j] = acc[j];
    if ((t & 15) == 0) lpart[slot][c0 >> 7] = lsum;
    __syncthreads();

    if (t < 128) {
        int head = t >> 4;
        float l = lpart[0][head] + lpart[1][head];
        float inv = 1.f / (l + 1e-16f);
        #pragma unroll
        for (int j = 0; j < 8; j++) {
            int c = t * 8 + j;
            part[0][c] = (part[0][c] + part[1][c]) * inv;
        }
    }
    __syncthreads();
    if (t < 128) {
        float ssum = 0.f;
        #pragma unroll
        for (int h = 0; h < 8; h++) ssum += part[0][h * 128 + t];
        float val = fmaxf(ssum * 0.125f + bias[t], 0.f);
        if (LAYER == 1) h_out[(size_t)dstn * CH + t] = val;
        else hrow[t] = val;
    }
    if (LAYER == 2) {
        __syncthreads();
        if (t < 64) {
            int j = t & 7, p8 = t >> 3;
            float v = 0.f;
            #pragma unroll
            for (int kk = 0; kk < 16; kk++) {
                int k = p8 * 16 + kk;
                v = fmaf(hrow[k], Wlin[k * 8 + j], v);
            }
            v += __shfl_xor(v, 8, 64);
            v += __shfl_xor(v, 16, 64);
            v += __shfl_xor(v, 32, 64);
            if (t < 8) out[(size_t)dstn * 8 + t] = v + blin[t];
        }
    }
}

extern "C" void kernel_launch(void* const* d_in, const int* in_sizes, int n_in,
                              void* d_out, int out_size, void* d_ws, size_t ws_size,
                              hipStream_t stream) {
    const float* x    = (const float*)d_in[0];
    const int*   ei   = (const int*)d_in[1];     // [2, E]
    const float* Wl1  = (const float*)d_in[2];
    const float* bl1  = (const float*)d_in[3];
    const float* Wr1  = (const float*)d_in[4];
    const float* br1  = (const float*)d_in[5];
    const float* att1 = (const float*)d_in[6];
    const float* b1   = (const float*)d_in[7];
    const float* Wl2  = (const float*)d_in[8];
    const float* bl2  = (const float*)d_in[9];
    const float* Wr2  = (const float*)d_in[10];
    const float* br2  = (const float*)d_in[11];
    const float* att2 = (const float*)d_in[12];
    const float* b2   = (const float*)d_in[13];
    const float* Wlin = (const float*)d_in[14];
    const float* blin = (const float*)d_in[15];
    float* out = (float*)d_out;

    const int* esrc = ei;
    const int* edst = ei + N_EDGES;

    // workspace layout
    char* p = (char*)d_ws;
    __half* xlh = (__half*)p;                  p += (size_t)N_NODES * HC * sizeof(__half);
    float*  xr  = (float*)p;                   p += (size_t)N_NODES * HC * sizeof(float);
    float*  h1  = (float*)p;                   p += (size_t)N_NODES * CH * sizeof(float);
    int* deg     = (int*)p;
    int* row_ptr = deg + N_NODES;              // N+1
    int* cursor  = row_ptr + N_NODES + 16;
    int* srcs    = cursor + N_NODES;           // N_TOT

    hipMemsetAsync(deg, 0, N_NODES * sizeof(int), stream);
    hist_kernel<<<(N_EDGES + 255) / 256, 256, 0, stream>>>(edst, deg);
    scan_kernel<<<1, 1024, 0, stream>>>(deg, row_ptr, cursor);
    scatter_kernel<<<(N_TOT + 255) / 256, 256, 0, stream>>>(esrc, edst, cursor, srcs);

    dim3 ggrid((N_NODES + 63) / 64, 8);
    gemm_xlxr<16><<<ggrid, 256, 0, stream>>>(x, Wl1, bl1, Wr1, br1, xlh, xr, N_NODES);
    gat_kernel<1><<<N_NODES, 256, 0, stream>>>(xlh, xr, att1, b1, row_ptr, srcs,
                                               h1, nullptr, nullptr, nullptr);
    gemm_xlxr<128><<<ggrid, 256, 0, stream>>>(h1, Wl2, bl2, Wr2, br2, xlh, xr, NAG);
    gat_kernel<2><<<NAG, 256, 0, stream>>>(xlh, xr, att2, b2, row_ptr, srcs,
                                           nullptr, Wlin, blin, out);
}

// Round 6
// 288.732 us; speedup vs baseline: 1.7475x; 1.1091x over previous
//
#include <hip/hip_runtime.h>
#include <hip/hip_fp16.h>
#include <math.h>

#define N_NODES 10000
#define N_EDGES 160000
#define N_TOT   170000   // edges + self loops
#define NAG     5000
#define HC      1024     // H*C_HID
#define CH      128
#define NEG     0.2f

typedef _Float16 f16x8 __attribute__((ext_vector_type(8)));
typedef float f32x4 __attribute__((ext_vector_type(4)));

// ---------------- CSR build ----------------
__global__ __launch_bounds__(256) void hist_kernel(const int* __restrict__ dst,
                                                   int* __restrict__ deg) {
    int e = blockIdx.x * 256 + threadIdx.x;
    if (e < N_EDGES) atomicAdd(&deg[dst[e]], 1);
}

__global__ __launch_bounds__(1024) void scan_kernel(const int* __restrict__ deg,
                                                    int* __restrict__ row_ptr,
                                                    int* __restrict__ cursor) {
    int t = threadIdx.x;
    const int CHK = 10;
    int base = t * CHK;
    int loc[CHK];
    int sum = 0;
    #pragma unroll
    for (int i = 0; i < CHK; i++) {
        int idx = base + i;
        int d = (idx < N_NODES) ? (deg[idx] + 1) : 0;  // +1 = self loop
        loc[i] = sum;
        sum += d;
    }
    __shared__ int part[1024];
    part[t] = sum;
    __syncthreads();
    for (int off = 1; off < 1024; off <<= 1) {
        int v = (t >= off) ? part[t - off] : 0;
        __syncthreads();
        part[t] += v;
        __syncthreads();
    }
    int pre = (t > 0) ? part[t - 1] : 0;
    #pragma unroll
    for (int i = 0; i < CHK; i++) {
        int idx = base + i;
        if (idx < N_NODES) {
            int v = pre + loc[i];
            row_ptr[idx] = v;
            cursor[idx] = v;
        }
    }
    if (t == 1023) row_ptr[N_NODES] = part[1023];
}

__global__ __launch_bounds__(256) void scatter_kernel(const int* __restrict__ src,
                                                      const int* __restrict__ dst,
                                                      int* __restrict__ cursor,
                                                      int* __restrict__ srcs) {
    int e = blockIdx.x * 256 + threadIdx.x;
    if (e < N_EDGES) {
        int p = atomicAdd(&cursor[dst[e]], 1);
        srcs[p] = src[e];
    } else if (e < N_TOT) {
        int i = e - N_EDGES;
        int p = atomicAdd(&cursor[i], 1);
        srcs[p] = i;                           // self loop
    }
}

// ---------------- W -> fp16 transposed [col][k] (layer1 zero-padded K 16->32) ----------------
__global__ __launch_bounds__(256) void convert_w(const float* __restrict__ Wl1, const float* __restrict__ Wr1,
                                                 const float* __restrict__ Wl2, const float* __restrict__ Wr2,
                                                 _Float16* __restrict__ w1l, _Float16* __restrict__ w1r,
                                                 _Float16* __restrict__ w2l, _Float16* __restrict__ w2r) {
    int gid = blockIdx.x * 256 + threadIdx.x;
    const int S1 = 1024 * 32, S2 = 1024 * 128;
    if (gid < 2 * S1) {
        const float* W = (gid < S1) ? Wl1 : Wr1;
        _Float16* o    = (gid < S1) ? w1l : w1r;
        int g = (gid < S1) ? gid : gid - S1;
        int col = g & 1023, k = g >> 10;
        float v = (k < 16) ? W[k * 1024 + col] : 0.f;
        o[col * 32 + k] = (_Float16)v;
    } else {
        int g = gid - 2 * S1;
        if (g >= 2 * S2) return;
        const float* W = (g < S2) ? Wl2 : Wr2;
        _Float16* o    = (g < S2) ? w2l : w2r;
        int gg = (g < S2) ? g : g - S2;
        int col = gg & 1023, k = gg >> 10;
        o[col * 128 + k] = (_Float16)W[k * 1024 + col];
    }
}

// ---------------- MFMA GEMM: [N,KA] x [KA,1024](+bias) -> xl (fp16) / xr (fp32) ----------------
// grid (ceil(N/64), 8): y<4 -> left (xl), y>=4 -> right (xr); colbase=(y&3)*256.
// Block tile 64 rows x 256 cols. Wave w: rows [16w,16w+16), 16 col-tiles of 16.
// v_mfma_f32_16x16x32_f16: A[m=lane&15][k=quad*8+j], B[k=quad*8+j][n=lane&15],
// D col=lane&15, row=quad*4+reg (m89/m118-verified layouts).
template <int K, int KA>   // K: padded K (mult of 32), KA: actual A columns
__global__ __launch_bounds__(256) void gemm_mfma(const float* __restrict__ A,
                                                 const _Float16* __restrict__ Whl, const float* __restrict__ bl,
                                                 const _Float16* __restrict__ Whr, const float* __restrict__ br,
                                                 _Float16* __restrict__ xl, float* __restrict__ xr,
                                                 int limitL, int limitR) {
    int rowblk = blockIdx.x * 64;
    bool right = blockIdx.y >= 4;
    if (rowblk >= (right ? limitR : limitL)) return;
    const _Float16* Wh = right ? Whr : Whl;
    const float* bs    = right ? br : bl;
    int colbase = (blockIdx.y & 3) * 256;
    int t = threadIdx.x;
    int w = t >> 6, l = t & 63;
    int m = l & 15, q = l >> 4;

    const int AS = K + 8;
    __shared__ __align__(16) _Float16 ash[64 * (K + 8)];

    // stage A tile -> fp16 LDS (zero-pad cols >= KA and rows >= N)
    for (int idx = t; idx < 64 * (K / 8); idx += 256) {
        int r  = idx / (K / 8);
        int c8 = (idx % (K / 8)) * 8;
        int row = rowblk + r;
        float4 v0 = make_float4(0.f, 0.f, 0.f, 0.f);
        float4 v1 = make_float4(0.f, 0.f, 0.f, 0.f);
        if (row < N_NODES && c8 < KA) {
            v0 = *(const float4*)(A + (size_t)row * KA + c8);
            v1 = *(const float4*)(A + (size_t)row * KA + c8 + 4);
        }
        _Float16* d = &ash[r * AS + c8];
        d[0] = (_Float16)v0.x; d[1] = (_Float16)v0.y; d[2] = (_Float16)v0.z; d[3] = (_Float16)v0.w;
        d[4] = (_Float16)v1.x; d[5] = (_Float16)v1.y; d[6] = (_Float16)v1.z; d[7] = (_Float16)v1.w;
    }
    __syncthreads();

    f32x4 acc[16];
    #pragma unroll
    for (int i = 0; i < 16; i++) acc[i] = (f32x4){0.f, 0.f, 0.f, 0.f};

    for (int k0 = 0; k0 < K; k0 += 32) {
        f16x8 af = *(const f16x8*)&ash[(w * 16 + m) * AS + k0 + q * 8];
        const _Float16* wp = Wh + (size_t)(colbase + m) * K + k0 + q * 8;
        #pragma unroll
        for (int tile = 0; tile < 16; tile++) {
            f16x8 bf = *(const f16x8*)(wp + (size_t)tile * 16 * K);
            acc[tile] = __builtin_amdgcn_mfma_f32_16x16x32_f16(af, bf, acc[tile], 0, 0, 0);
        }
    }

    float bv[16];
    #pragma unroll
    for (int tile = 0; tile < 16; tile++) bv[tile] = bs[colbase + tile * 16 + m];

    #pragma unroll
    for (int tile = 0; tile < 16; tile++) {
        int col = colbase + tile * 16 + m;
        #pragma unroll
        for (int reg = 0; reg < 4; reg++) {
            int row = rowblk + w * 16 + q * 4 + reg;
            if (row < N_NODES) {
                float v = acc[tile][reg] + bv[tile];
                if (right) xr[(size_t)row * HC + col] = v;
                else       xl[(size_t)row * HC + col] = (_Float16)v;
            }
        }
    }
}

// ---------------- Fused GATv2 attention + aggregation ----------------
// Block per dst. Thread t: slot = t>>7 (edge A/B), owns 8 channels c0=(t&127)*8.
__device__ __forceinline__ void unpack8(float4 raw, float* f) {
    __half2* hp = (__half2*)&raw;
    #pragma unroll
    for (int j = 0; j < 4; j++) {
        float2 fj = __half22float2(hp[j]);
        f[j * 2] = fj.x;
        f[j * 2 + 1] = fj.y;
    }
}

template <int LAYER>
__global__ __launch_bounds__(256) void gat_kernel(const __half* __restrict__ xl,
                                                  const float* __restrict__ xr,
                                                  const float* __restrict__ att,
                                                  const float* __restrict__ bias,
                                                  const int* __restrict__ row_ptr,
                                                  const int* __restrict__ srcs,
                                                  float* __restrict__ h_out,       // LAYER==1
                                                  const float* __restrict__ Wlin,  // LAYER==2
                                                  const float* __restrict__ blin,
                                                  float* __restrict__ out) {
    int dstn = blockIdx.x;
    int t = threadIdx.x;
    int slot = t >> 7;
    int c0 = (t & 127) * 8;

    float xrv[8], attv[8];
    {
        float4 a0 = *(const float4*)(xr + (size_t)dstn * HC + c0);
        float4 a1 = *(const float4*)(xr + (size_t)dstn * HC + c0 + 4);
        xrv[0] = a0.x; xrv[1] = a0.y; xrv[2] = a0.z; xrv[3] = a0.w;
        xrv[4] = a1.x; xrv[5] = a1.y; xrv[6] = a1.z; xrv[7] = a1.w;
        float4 b0 = *(const float4*)(att + c0);
        float4 b1 = *(const float4*)(att + c0 + 4);
        attv[0] = b0.x; attv[1] = b0.y; attv[2] = b0.z; attv[3] = b0.w;
        attv[4] = b1.x; attv[5] = b1.y; attv[6] = b1.z; attv[7] = b1.w;
    }

    float acc[8];
    #pragma unroll
    for (int j = 0; j < 8; j++) acc[j] = 0.f;
    float lsum = 0.f;

    int e0 = row_ptr[dstn], e1 = row_ptr[dstn + 1];
    int e = e0;
    for (; e + 8 <= e1; e += 8) {
        int s[4];
        #pragma unroll
        for (int i = 0; i < 4; i++) s[i] = srcs[e + slot + 2 * i];
        float4 raw[4];
        #pragma unroll
        for (int i = 0; i < 4; i++) raw[i] = *(const float4*)(xl + (size_t)s[i] * HC + c0);
        #pragma unroll
        for (int i = 0; i < 4; i++) {
            float f[8];
            unpack8(raw[i], f);
            float p = 0.f;
            #pragma unroll
            for (int j = 0; j < 8; j++) {
                float z = f[j] + xrv[j];
                z = fmaxf(z, NEG * z);
                p = fmaf(z, attv[j], p);
            }
            p += __shfl_xor(p, 1, 64);
            p += __shfl_xor(p, 2, 64);
            p += __shfl_xor(p, 4, 64);
            p += __shfl_xor(p, 8, 64);
            float w = __expf(p);
            lsum += w;
            #pragma unroll
            for (int j = 0; j < 8; j++) acc[j] = fmaf(w, f[j], acc[j]);
        }
    }
    for (; e < e1; e += 2) {
        int ee = e + slot;
        bool valid = ee < e1;
        int s = srcs[valid ? ee : e];
        float4 raw = *(const float4*)(xl + (size_t)s * HC + c0);
        float f[8];
        unpack8(raw, f);
        float p = 0.f;
        #pragma unroll
        for (int j = 0; j < 8; j++) {
            float z = f[j] + xrv[j];
            z = fmaxf(z, NEG * z);
            p = fmaf(z, attv[j], p);
        }
        p += __shfl_xor(p, 1, 64);
        p += __shfl_xor(p, 2, 64);
        p += __shfl_xor(p, 4, 64);
        p += __shfl_xor(p, 8, 64);
        float w = valid ? __expf(p) : 0.f;
        lsum += w;
        #pragma unroll
        for (int j = 0; j < 8; j++) acc[j] = fmaf(w, f[j], acc[j]);
    }

    __shared__ float part[2][HC];
    __shared__ float lpart[2][8];
    __shared__ float hrow[CH];
    #pragma unroll
    for (int j = 0; j < 8; j++) part[slot][c0 + j] = acc[j];
    if ((t & 15) == 0) lpart[slot][c0 >> 7] = lsum;
    __syncthreads();

    if (t < 128) {
        int head = t >> 4;
        float l = lpart[0][head] + lpart[1][head];
        float inv = 1.f / (l + 1e-16f);
        #pragma unroll
        for (int j = 0; j < 8; j++) {
            int c = t * 8 + j;
            part[0][c] = (part[0][c] + part[1][c]) * inv;
        }
    }
    __syncthreads();
    if (t < 128) {
        float ssum = 0.f;
        #pragma unroll
        for (int h = 0; h < 8; h++) ssum += part[0][h * 128 + t];
        float val = fmaxf(ssum * 0.125f + bias[t], 0.f);
        if (LAYER == 1) h_out[(size_t)dstn * CH + t] = val;
        else hrow[t] = val;
    }
    if (LAYER == 2) {
        __syncthreads();
        if (t < 64) {
            int j = t & 7, p8 = t >> 3;
            float v = 0.f;
            #pragma unroll
            for (int kk = 0; kk < 16; kk++) {
                int k = p8 * 16 + kk;
                v = fmaf(hrow[k], Wlin[k * 8 + j], v);
            }
            v += __shfl_xor(v, 8, 64);
            v += __shfl_xor(v, 16, 64);
            v += __shfl_xor(v, 32, 64);
            if (t < 8) out[(size_t)dstn * 8 + t] = v + blin[t];
        }
    }
}

extern "C" void kernel_launch(void* const* d_in, const int* in_sizes, int n_in,
                              void* d_out, int out_size, void* d_ws, size_t ws_size,
                              hipStream_t stream) {
    const float* x    = (const float*)d_in[0];
    const int*   ei   = (const int*)d_in[1];     // [2, E]
    const float* Wl1  = (const float*)d_in[2];
    const float* bl1  = (const float*)d_in[3];
    const float* Wr1  = (const float*)d_in[4];
    const float* br1  = (const float*)d_in[5];
    const float* att1 = (const float*)d_in[6];
    const float* b1   = (const float*)d_in[7];
    const float* Wl2  = (const float*)d_in[8];
    const float* bl2  = (const float*)d_in[9];
    const float* Wr2  = (const float*)d_in[10];
    const float* br2  = (const float*)d_in[11];
    const float* att2 = (const float*)d_in[12];
    const float* b2   = (const float*)d_in[13];
    const float* Wlin = (const float*)d_in[14];
    const float* blin = (const float*)d_in[15];
    float* out = (float*)d_out;

    const int* esrc = ei;
    const int* edst = ei + N_EDGES;

    // workspace layout (all chunks 16B-aligned)
    char* p = (char*)d_ws;
    __half* xlh = (__half*)p;                  p += (size_t)N_NODES * HC * sizeof(__half);
    float*  xr  = (float*)p;                   p += (size_t)N_NODES * HC * sizeof(float);
    float*  h1  = (float*)p;                   p += (size_t)N_NODES * CH * sizeof(float);
    _Float16* w1l = (_Float16*)p;              p += 1024 * 32 * sizeof(_Float16);
    _Float16* w1r = (_Float16*)p;              p += 1024 * 32 * sizeof(_Float16);
    _Float16* w2l = (_Float16*)p;              p += 1024 * 128 * sizeof(_Float16);
    _Float16* w2r = (_Float16*)p;              p += 1024 * 128 * sizeof(_Float16);
    int* deg     = (int*)p;
    int* row_ptr = deg + N_NODES;              // N+1
    int* cursor  = row_ptr + N_NODES + 16;
    int* srcs    = cursor + N_NODES;           // N_TOT

    hipMemsetAsync(deg, 0, N_NODES * sizeof(int), stream);
    hist_kernel<<<(N_EDGES + 255) / 256, 256, 0, stream>>>(edst, deg);
    scan_kernel<<<1, 1024, 0, stream>>>(deg, row_ptr, cursor);
    scatter_kernel<<<(N_TOT + 255) / 256, 256, 0, stream>>>(esrc, edst, cursor, srcs);
    convert_w<<<1280, 256, 0, stream>>>(Wl1, Wr1, Wl2, Wr2, w1l, w1r, w2l, w2r);

    dim3 ggrid((N_NODES + 63) / 64, 8);
    gemm_mfma<32, 16><<<ggrid, 256, 0, stream>>>(x, w1l, bl1, w1r, br1,
                                                 (_Float16*)xlh, xr, N_NODES, N_NODES);
    gat_kernel<1><<<N_NODES, 256, 0, stream>>>(xlh, xr, att1, b1, row_ptr, srcs,
                                               h1, nullptr, nullptr, nullptr);
    gemm_mfma<128, 128><<<ggrid, 256, 0, stream>>>(h1, w2l, bl2, w2r, br2,
                                                   (_Float16*)xlh, xr, N_NODES, NAG);
    gat_kernel<2><<<NAG, 256, 0, stream>>>(xlh, xr, att2, b2, row_ptr, srcs,
                                           nullptr, Wlin, blin, out);
}

// Round 7
// 287.437 us; speedup vs baseline: 1.7554x; 1.0045x over previous
//
#include <hip/hip_runtime.h>
#include <hip/hip_fp16.h>
#include <math.h>

#define N_NODES 10000
#define N_EDGES 160000
#define N_TOT   170000   // edges + self loops
#define NAG     5000
#define HC      1024     // H*C_HID
#define CH      128
#define NEG     0.2f

typedef _Float16 f16x8 __attribute__((ext_vector_type(8)));
typedef float f32x4 __attribute__((ext_vector_type(4)));

// ---------------- CSR build ----------------
__global__ __launch_bounds__(256) void hist_kernel(const int* __restrict__ dst,
                                                   int* __restrict__ deg) {
    int e = blockIdx.x * 256 + threadIdx.x;
    if (e < N_EDGES) atomicAdd(&deg[dst[e]], 1);
}

__global__ __launch_bounds__(1024) void scan_kernel(const int* __restrict__ deg,
                                                    int* __restrict__ row_ptr,
                                                    int* __restrict__ cursor) {
    int t = threadIdx.x;
    const int CHK = 10;
    int base = t * CHK;
    int loc[CHK];
    int sum = 0;
    #pragma unroll
    for (int i = 0; i < CHK; i++) {
        int idx = base + i;
        int d = (idx < N_NODES) ? (deg[idx] + 1) : 0;  // +1 = self loop
        loc[i] = sum;
        sum += d;
    }
    __shared__ int part[1024];
    part[t] = sum;
    __syncthreads();
    for (int off = 1; off < 1024; off <<= 1) {
        int v = (t >= off) ? part[t - off] : 0;
        __syncthreads();
        part[t] += v;
        __syncthreads();
    }
    int pre = (t > 0) ? part[t - 1] : 0;
    #pragma unroll
    for (int i = 0; i < CHK; i++) {
        int idx = base + i;
        if (idx < N_NODES) {
            int v = pre + loc[i];
            row_ptr[idx] = v;
            cursor[idx] = v;
        }
    }
    if (t == 1023) row_ptr[N_NODES] = part[1023];
}

__global__ __launch_bounds__(256) void scatter_kernel(const int* __restrict__ src,
                                                      const int* __restrict__ dst,
                                                      int* __restrict__ cursor,
                                                      int* __restrict__ srcs) {
    int e = blockIdx.x * 256 + threadIdx.x;
    if (e < N_EDGES) {
        int p = atomicAdd(&cursor[dst[e]], 1);
        srcs[p] = src[e];
    } else if (e < N_TOT) {
        int i = e - N_EDGES;
        int p = atomicAdd(&cursor[i], 1);
        srcs[p] = i;                           // self loop
    }
}

// ---------------- W -> fp16 transposed [col][k] (layer1 zero-padded K 16->32) ----------------
__global__ __launch_bounds__(256) void convert_w(const float* __restrict__ Wl1, const float* __restrict__ Wr1,
                                                 const float* __restrict__ Wl2, const float* __restrict__ Wr2,
                                                 _Float16* __restrict__ w1l, _Float16* __restrict__ w1r,
                                                 _Float16* __restrict__ w2l, _Float16* __restrict__ w2r) {
    int gid = blockIdx.x * 256 + threadIdx.x;
    const int S1 = 1024 * 32, S2 = 1024 * 128;
    if (gid < 2 * S1) {
        const float* W = (gid < S1) ? Wl1 : Wr1;
        _Float16* o    = (gid < S1) ? w1l : w1r;
        int g = (gid < S1) ? gid : gid - S1;
        int col = g & 1023, k = g >> 10;
        float v = (k < 16) ? W[k * 1024 + col] : 0.f;
        o[col * 32 + k] = (_Float16)v;
    } else {
        int g = gid - 2 * S1;
        if (g >= 2 * S2) return;
        const float* W = (g < S2) ? Wl2 : Wr2;
        _Float16* o    = (g < S2) ? w2l : w2r;
        int gg = (g < S2) ? g : g - S2;
        int col = gg & 1023, k = gg >> 10;
        o[col * 128 + k] = (_Float16)W[k * 1024 + col];
    }
}

// ---------------- MFMA GEMM: [N,KA] x [KA,1024](+bias) -> xl (fp16) / xr (fp32) ----------------
template <int K, int KA>   // K: padded K (mult of 32), KA: actual A columns
__global__ __launch_bounds__(256) void gemm_mfma(const float* __restrict__ A,
                                                 const _Float16* __restrict__ Whl, const float* __restrict__ bl,
                                                 const _Float16* __restrict__ Whr, const float* __restrict__ br,
                                                 _Float16* __restrict__ xl, float* __restrict__ xr,
                                                 int limitL, int limitR) {
    int rowblk = blockIdx.x * 64;
    bool right = blockIdx.y >= 4;
    if (rowblk >= (right ? limitR : limitL)) return;
    const _Float16* Wh = right ? Whr : Whl;
    const float* bs    = right ? br : bl;
    int colbase = (blockIdx.y & 3) * 256;
    int t = threadIdx.x;
    int w = t >> 6, l = t & 63;
    int m = l & 15, q = l >> 4;

    const int AS = K + 8;
    __shared__ __align__(16) _Float16 ash[64 * (K + 8)];

    for (int idx = t; idx < 64 * (K / 8); idx += 256) {
        int r  = idx / (K / 8);
        int c8 = (idx % (K / 8)) * 8;
        int row = rowblk + r;
        float4 v0 = make_float4(0.f, 0.f, 0.f, 0.f);
        float4 v1 = make_float4(0.f, 0.f, 0.f, 0.f);
        if (row < N_NODES && c8 < KA) {
            v0 = *(const float4*)(A + (size_t)row * KA + c8);
            v1 = *(const float4*)(A + (size_t)row * KA + c8 + 4);
        }
        _Float16* d = &ash[r * AS + c8];
        d[0] = (_Float16)v0.x; d[1] = (_Float16)v0.y; d[2] = (_Float16)v0.z; d[3] = (_Float16)v0.w;
        d[4] = (_Float16)v1.x; d[5] = (_Float16)v1.y; d[6] = (_Float16)v1.z; d[7] = (_Float16)v1.w;
    }
    __syncthreads();

    f32x4 acc[16];
    #pragma unroll
    for (int i = 0; i < 16; i++) acc[i] = (f32x4){0.f, 0.f, 0.f, 0.f};

    for (int k0 = 0; k0 < K; k0 += 32) {
        f16x8 af = *(const f16x8*)&ash[(w * 16 + m) * AS + k0 + q * 8];
        const _Float16* wp = Wh + (size_t)(colbase + m) * K + k0 + q * 8;
        #pragma unroll
        for (int tile = 0; tile < 16; tile++) {
            f16x8 bf = *(const f16x8*)(wp + (size_t)tile * 16 * K);
            acc[tile] = __builtin_amdgcn_mfma_f32_16x16x32_f16(af, bf, acc[tile], 0, 0, 0);
        }
    }

    float bv[16];
    #pragma unroll
    for (int tile = 0; tile < 16; tile++) bv[tile] = bs[colbase + tile * 16 + m];

    #pragma unroll
    for (int tile = 0; tile < 16; tile++) {
        int col = colbase + tile * 16 + m;
        #pragma unroll
        for (int reg = 0; reg < 4; reg++) {
            int row = rowblk + w * 16 + q * 4 + reg;
            if (row < N_NODES) {
                float v = acc[tile][reg] + bv[tile];
                if (right) xr[(size_t)row * HC + col] = v;
                else       xl[(size_t)row * HC + col] = (_Float16)v;
            }
        }
    }
}

// ---------------- Fused GATv2 attention + aggregation ----------------
// Block per dst. Thread t: slot = t>>7 (edge A/B), owns 8 channels c0=(t&127)*8.
// Pipeline: 16 edges/block-step (8/slot, 8 dwordx4 in flight/wave) -> 4 -> masked 2.
__device__ __forceinline__ void unpack8(float4 raw, float* f) {
    __half2* hp = (__half2*)&raw;
    #pragma unroll
    for (int j = 0; j < 4; j++) {
        float2 fj = __half22float2(hp[j]);
        f[j * 2] = fj.x;
        f[j * 2 + 1] = fj.y;
    }
}

__device__ __forceinline__ void edge_accum(float4 raw, const float* xrv, const float* attv,
                                           float& lsum, float* acc) {
    float f[8];
    unpack8(raw, f);
    float p = 0.f;
    #pragma unroll
    for (int j = 0; j < 8; j++) {
        float z = f[j] + xrv[j];
        z = fmaxf(z, NEG * z);
        p = fmaf(z, attv[j], p);
    }
    p += __shfl_xor(p, 1, 64);
    p += __shfl_xor(p, 2, 64);
    p += __shfl_xor(p, 4, 64);
    p += __shfl_xor(p, 8, 64);
    float w = __expf(p);
    lsum += w;
    #pragma unroll
    for (int j = 0; j < 8; j++) acc[j] = fmaf(w, f[j], acc[j]);
}

template <int LAYER>
__global__ __launch_bounds__(256) void gat_kernel(const __half* __restrict__ xl,
                                                  const float* __restrict__ xr,
                                                  const float* __restrict__ att,
                                                  const float* __restrict__ bias,
                                                  const int* __restrict__ row_ptr,
                                                  const int* __restrict__ srcs,
                                                  float* __restrict__ h_out,       // LAYER==1
                                                  const float* __restrict__ Wlin,  // LAYER==2
                                                  const float* __restrict__ blin,
                                                  float* __restrict__ out) {
    int dstn = blockIdx.x;
    int t = threadIdx.x;
    int slot = t >> 7;
    int c0 = (t & 127) * 8;

    float xrv[8], attv[8];
    {
        float4 a0 = *(const float4*)(xr + (size_t)dstn * HC + c0);
        float4 a1 = *(const float4*)(xr + (size_t)dstn * HC + c0 + 4);
        xrv[0] = a0.x; xrv[1] = a0.y; xrv[2] = a0.z; xrv[3] = a0.w;
        xrv[4] = a1.x; xrv[5] = a1.y; xrv[6] = a1.z; xrv[7] = a1.w;
        float4 b0 = *(const float4*)(att + c0);
        float4 b1 = *(const float4*)(att + c0 + 4);
        attv[0] = b0.x; attv[1] = b0.y; attv[2] = b0.z; attv[3] = b0.w;
        attv[4] = b1.x; attv[5] = b1.y; attv[6] = b1.z; attv[7] = b1.w;
    }

    float acc[8];
    #pragma unroll
    for (int j = 0; j < 8; j++) acc[j] = 0.f;
    float lsum = 0.f;

    int e0 = row_ptr[dstn], e1 = row_ptr[dstn + 1];
    int e = e0;
    // 16 edges per block step (8 per slot): 8 gathers in flight per wave
    for (; e + 16 <= e1; e += 16) {
        int s[8];
        #pragma unroll
        for (int i = 0; i < 8; i++) s[i] = srcs[e + slot + 2 * i];
        float4 raw[8];
        #pragma unroll
        for (int i = 0; i < 8; i++) raw[i] = *(const float4*)(xl + (size_t)s[i] * HC + c0);
        #pragma unroll
        for (int i = 0; i < 8; i++) edge_accum(raw[i], xrv, attv, lsum, acc);
    }
    // 4 edges per block step (2 per slot)
    for (; e + 4 <= e1; e += 4) {
        int s[2];
        #pragma unroll
        for (int i = 0; i < 2; i++) s[i] = srcs[e + slot + 2 * i];
        float4 raw[2];
        #pragma unroll
        for (int i = 0; i < 2; i++) raw[i] = *(const float4*)(xl + (size_t)s[i] * HC + c0);
        #pragma unroll
        for (int i = 0; i < 2; i++) edge_accum(raw[i], xrv, attv, lsum, acc);
    }
    // masked tail (block-uniform bound)
    for (; e < e1; e += 2) {
        int ee = e + slot;
        bool valid = ee < e1;
        int s = srcs[valid ? ee : e];
        float4 raw = *(const float4*)(xl + (size_t)s * HC + c0);
        float f[8];
        unpack8(raw, f);
        float p = 0.f;
        #pragma unroll
        for (int j = 0; j < 8; j++) {
            float z = f[j] + xrv[j];
            z = fmaxf(z, NEG * z);
            p = fmaf(z, attv[j], p);
        }
        p += __shfl_xor(p, 1, 64);
        p += __shfl_xor(p, 2, 64);
        p += __shfl_xor(p, 4, 64);
        p += __shfl_xor(p, 8, 64);
        float w = valid ? __expf(p) : 0.f;
        lsum += w;
        #pragma unroll
        for (int j = 0; j < 8; j++) acc[j] = fmaf(w, f[j], acc[j]);
    }

    __shared__ float part[2][HC];
    __shared__ float lpart[2][8];
    __shared__ float hrow[CH];
    #pragma unroll
    for (int j = 0; j < 8; j++) part[slot][c0 + j] = acc[j];
    if ((t & 15) == 0) lpart[slot][c0 >> 7] = lsum;
    __syncthreads();

    if (t < 128) {
        int head = t >> 4;
        float l = lpart[0][head] + lpart[1][head];
        float inv = 1.f / (l + 1e-16f);
        #pragma unroll
        for (int j = 0; j < 8; j++) {
            int c = t * 8 + j;
            part[0][c] = (part[0][c] + part[1][c]) * inv;
        }
    }
    __syncthreads();
    if (t < 128) {
        float ssum = 0.f;
        #pragma unroll
        for (int h = 0; h < 8; h++) ssum += part[0][h * 128 + t];
        float val = fmaxf(ssum * 0.125f + bias[t], 0.f);
        if (LAYER == 1) h_out[(size_t)dstn * CH + t] = val;
        else hrow[t] = val;
    }
    if (LAYER == 2) {
        __syncthreads();
        if (t < 64) {
            int j = t & 7, p8 = t >> 3;
            float v = 0.f;
            #pragma unroll
            for (int kk = 0; kk < 16; kk++) {
                int k = p8 * 16 + kk;
                v = fmaf(hrow[k], Wlin[k * 8 + j], v);
            }
            v += __shfl_xor(v, 8, 64);
            v += __shfl_xor(v, 16, 64);
            v += __shfl_xor(v, 32, 64);
            if (t < 8) out[(size_t)dstn * 8 + t] = v + blin[t];
        }
    }
}

extern "C" void kernel_launch(void* const* d_in, const int* in_sizes, int n_in,
                              void* d_out, int out_size, void* d_ws, size_t ws_size,
                              hipStream_t stream) {
    const float* x    = (const float*)d_in[0];
    const int*   ei   = (const int*)d_in[1];     // [2, E]
    const float* Wl1  = (const float*)d_in[2];
    const float* bl1  = (const float*)d_in[3];
    const float* Wr1  = (const float*)d_in[4];
    const float* br1  = (const float*)d_in[5];
    const float* att1 = (const float*)d_in[6];
    const float* b1   = (const float*)d_in[7];
    const float* Wl2  = (const float*)d_in[8];
    const float* bl2  = (const float*)d_in[9];
    const float* Wr2  = (const float*)d_in[10];
    const float* br2  = (const float*)d_in[11];
    const float* att2 = (const float*)d_in[12];
    const float* b2   = (const float*)d_in[13];
    const float* Wlin = (const float*)d_in[14];
    const float* blin = (const float*)d_in[15];
    float* out = (float*)d_out;

    const int* esrc = ei;
    const int* edst = ei + N_EDGES;

    // workspace layout (all chunks 16B-aligned)
    char* p = (char*)d_ws;
    __half* xlh = (__half*)p;                  p += (size_t)N_NODES * HC * sizeof(__half);
    float*  xr  = (float*)p;                   p += (size_t)N_NODES * HC * sizeof(float);
    float*  h1  = (float*)p;                   p += (size_t)N_NODES * CH * sizeof(float);
    _Float16* w1l = (_Float16*)p;              p += 1024 * 32 * sizeof(_Float16);
    _Float16* w1r = (_Float16*)p;              p += 1024 * 32 * sizeof(_Float16);
    _Float16* w2l = (_Float16*)p;              p += 1024 * 128 * sizeof(_Float16);
    _Float16* w2r = (_Float16*)p;              p += 1024 * 128 * sizeof(_Float16);
    int* deg     = (int*)p;
    int* row_ptr = deg + N_NODES;              // N+1
    int* cursor  = row_ptr + N_NODES + 16;
    int* srcs    = cursor + N_NODES;           // N_TOT

    hipMemsetAsync(deg, 0, N_NODES * sizeof(int), stream);
    hist_kernel<<<(N_EDGES + 255) / 256, 256, 0, stream>>>(edst, deg);
    scan_kernel<<<1, 1024, 0, stream>>>(deg, row_ptr, cursor);
    scatter_kernel<<<(N_TOT + 255) / 256, 256, 0, stream>>>(esrc, edst, cursor, srcs);
    convert_w<<<1280, 256, 0, stream>>>(Wl1, Wr1, Wl2, Wr2, w1l, w1r, w2l, w2r);

    dim3 ggrid((N_NODES + 63) / 64, 8);
    gemm_mfma<32, 16><<<ggrid, 256, 0, stream>>>(x, w1l, bl1, w1r, br1,
                                                 (_Float16*)xlh, xr, N_NODES, N_NODES);
    gat_kernel<1><<<N_NODES, 256, 0, stream>>>(xlh, xr, att1, b1, row_ptr, srcs,
                                               h1, nullptr, nullptr, nullptr);
    gemm_mfma<128, 128><<<ggrid, 256, 0, stream>>>(h1, w2l, bl2, w2r, br2,
                                                   (_Float16*)xlh, xr, N_NODES, NAG);
    gat_kernel<2><<<NAG, 256, 0, stream>>>(xlh, xr, att2, b2, row_ptr, srcs,
                                           nullptr, Wlin, blin, out);
}

// Round 9
// 277.068 us; speedup vs baseline: 1.8211x; 1.0374x over previous
//
#include <hip/hip_runtime.h>
#include <hip/hip_fp16.h>
#include <math.h>

#define N_NODES 10000
#define N_EDGES 160000
#define N_TOT   170000   // edges + self loops
#define NAG     5000
#define HC      1024     // H*C_HID
#define CH      128
#define NEG     0.2f

typedef _Float16 f16x8 __attribute__((ext_vector_type(8)));
typedef _Float16 f16x2 __attribute__((ext_vector_type(2)));
typedef float f32x4 __attribute__((ext_vector_type(4)));

// ---------------- CSR build ----------------
__global__ __launch_bounds__(256) void hist_kernel(const int* __restrict__ dst,
                                                   int* __restrict__ deg) {
    int e = blockIdx.x * 256 + threadIdx.x;
    if (e < N_EDGES) atomicAdd(&deg[dst[e]], 1);
}

__global__ __launch_bounds__(1024) void scan_kernel(const int* __restrict__ deg,
                                                    int* __restrict__ row_ptr,
                                                    int* __restrict__ cursor) {
    int t = threadIdx.x;
    const int CHK = 10;
    int base = t * CHK;
    int loc[CHK];
    int sum = 0;
    #pragma unroll
    for (int i = 0; i < CHK; i++) {
        int idx = base + i;
        int d = (idx < N_NODES) ? (deg[idx] + 1) : 0;  // +1 = self loop
        loc[i] = sum;
        sum += d;
    }
    __shared__ int part[1024];
    part[t] = sum;
    __syncthreads();
    for (int off = 1; off < 1024; off <<= 1) {
        int v = (t >= off) ? part[t - off] : 0;
        __syncthreads();
        part[t] += v;
        __syncthreads();
    }
    int pre = (t > 0) ? part[t - 1] : 0;
    #pragma unroll
    for (int i = 0; i < CHK; i++) {
        int idx = base + i;
        if (idx < N_NODES) {
            int v = pre + loc[i];
            row_ptr[idx] = v;
            cursor[idx] = v;
        }
    }
    if (t == 1023) row_ptr[N_NODES] = part[1023];
}

__global__ __launch_bounds__(256) void scatter_kernel(const int* __restrict__ src,
                                                      const int* __restrict__ dst,
                                                      int* __restrict__ cursor,
                                                      int* __restrict__ srcs) {
    int e = blockIdx.x * 256 + threadIdx.x;
    if (e < N_EDGES) {
        int p = atomicAdd(&cursor[dst[e]], 1);
        srcs[p] = src[e];
    } else if (e < N_TOT) {
        int i = e - N_EDGES;
        int p = atomicAdd(&cursor[i], 1);
        srcs[p] = i;                           // self loop
    }
}

// ---------------- W -> fp16 transposed [col][k] (layer1 zero-padded K 16->32) ----------------
__global__ __launch_bounds__(256) void convert_w(const float* __restrict__ Wl1, const float* __restrict__ Wr1,
                                                 const float* __restrict__ Wl2, const float* __restrict__ Wr2,
                                                 _Float16* __restrict__ w1l, _Float16* __restrict__ w1r,
                                                 _Float16* __restrict__ w2l, _Float16* __restrict__ w2r) {
    int gid = blockIdx.x * 256 + threadIdx.x;
    const int S1 = 1024 * 32, S2 = 1024 * 128;
    if (gid < 2 * S1) {
        const float* W = (gid < S1) ? Wl1 : Wr1;
        _Float16* o    = (gid < S1) ? w1l : w1r;
        int g = (gid < S1) ? gid : gid - S1;
        int col = g & 1023, k = g >> 10;
        float v = (k < 16) ? W[k * 1024 + col] : 0.f;
        o[col * 32 + k] = (_Float16)v;
    } else {
        int g = gid - 2 * S1;
        if (g >= 2 * S2) return;
        const float* W = (g < S2) ? Wl2 : Wr2;
        _Float16* o    = (g < S2) ? w2l : w2r;
        int gg = (g < S2) ? g : g - S2;
        int col = gg & 1023, k = gg >> 10;
        o[col * 128 + k] = (_Float16)W[k * 1024 + col];
    }
}

// ---------------- MFMA GEMM: [N,KA] x [KA,1024](+bias) -> xl (fp16) / xr (fp32) ----------------
// Block tile 64 rows x 256 cols; wave w rows [16w,16w+16), 16 col-tiles.
// Epilogue: LDS transpose (chunks of 64 cols) -> coalesced vectorized stores.
template <int K, int KA>   // K: padded K (mult of 32), KA: actual A columns
__global__ __launch_bounds__(256) void gemm_mfma(const float* __restrict__ A,
                                                 const _Float16* __restrict__ Whl, const float* __restrict__ bl,
                                                 const _Float16* __restrict__ Whr, const float* __restrict__ br,
                                                 _Float16* __restrict__ xl, float* __restrict__ xr,
                                                 int limitL, int limitR) {
    int rowblk = blockIdx.x * 64;
    bool right = blockIdx.y >= 4;
    if (rowblk >= (right ? limitR : limitL)) return;
    const _Float16* Wh = right ? Whr : Whl;
    const float* bs    = right ? br : bl;
    int colbase = (blockIdx.y & 3) * 256;
    int t = threadIdx.x;
    int w = t >> 6, l = t & 63;
    int m = l & 15, q = l >> 4;

    const int AS = K + 8;
    __shared__ __align__(16) _Float16 ash[64 * (K + 8)];
    __shared__ __align__(16) float eps[64][68];

    // stage A tile -> fp16 LDS (packed b128 writes)
    for (int idx = t; idx < 64 * (K / 8); idx += 256) {
        int r  = idx / (K / 8);
        int c8 = (idx % (K / 8)) * 8;
        int row = rowblk + r;
        float4 v0 = make_float4(0.f, 0.f, 0.f, 0.f);
        float4 v1 = make_float4(0.f, 0.f, 0.f, 0.f);
        if (row < N_NODES && c8 < KA) {
            v0 = *(const float4*)(A + (size_t)row * KA + c8);
            v1 = *(const float4*)(A + (size_t)row * KA + c8 + 4);
        }
        f16x8 hv;
        hv[0] = (_Float16)v0.x; hv[1] = (_Float16)v0.y; hv[2] = (_Float16)v0.z; hv[3] = (_Float16)v0.w;
        hv[4] = (_Float16)v1.x; hv[5] = (_Float16)v1.y; hv[6] = (_Float16)v1.z; hv[7] = (_Float16)v1.w;
        *(f16x8*)&ash[r * AS + c8] = hv;
    }
    __syncthreads();

    f32x4 acc[16];
    #pragma unroll
    for (int i = 0; i < 16; i++) acc[i] = (f32x4){0.f, 0.f, 0.f, 0.f};

    for (int k0 = 0; k0 < K; k0 += 32) {
        f16x8 af = *(const f16x8*)&ash[(w * 16 + m) * AS + k0 + q * 8];
        const _Float16* wp = Wh + (size_t)(colbase + m) * K + k0 + q * 8;
        #pragma unroll
        for (int tile = 0; tile < 16; tile++) {
            f16x8 bf = *(const f16x8*)(wp + (size_t)tile * 16 * K);
            acc[tile] = __builtin_amdgcn_mfma_f32_16x16x32_f16(af, bf, acc[tile], 0, 0, 0);
        }
    }

    float bv[16];
    #pragma unroll
    for (int tile = 0; tile < 16; tile++) bv[tile] = bs[colbase + tile * 16 + m];

    // epilogue: 4 chunks of 64 cols, via LDS, coalesced stores
    for (int cg = 0; cg < 4; cg++) {
        __syncthreads();
        #pragma unroll
        for (int tt = 0; tt < 4; tt++) {
            int tile = cg * 4 + tt;
            int cl = tt * 16 + m;
            #pragma unroll
            for (int reg = 0; reg < 4; reg++)
                eps[w * 16 + q * 4 + reg][cl] = acc[tile][reg] + bv[tile];
        }
        __syncthreads();
        int colg = colbase + cg * 64;
        int cc = (t & 15) * 4;
        #pragma unroll
        for (int it = 0; it < 4; it++) {
            int r = it * 16 + (t >> 4);
            int row = rowblk + r;
            if (row < N_NODES) {
                float4 v = *(const float4*)&eps[r][cc];
                if (right) {
                    *(float4*)(xr + (size_t)row * HC + colg + cc) = v;
                } else {
                    __half2 h01 = __floats2half2_rn(v.x, v.y);
                    __half2 h23 = __floats2half2_rn(v.z, v.w);
                    float2 st;
                    st.x = *(float*)&h01;
                    st.y = *(float*)&h23;
                    *(float2*)(xl + (size_t)row * HC + colg + cc) = st;
                }
            }
        }
    }
}

// ---------------- Fused GATv2 attention + aggregation ----------------
// Block per dst. Thread t: slot = t>>7, owns 8 channels c0=(t&127)*8.
// Edge math packed fp16 (v_pk_add/mul/max via asm for max); softmax/acc fp32.
__device__ __forceinline__ __half2 pk_max(__half2 a, __half2 b) {
    __half2 r;
    asm volatile("v_pk_max_f16 %0, %1, %2" : "=v"(r) : "v"(a), "v"(b));
    return r;
}

__device__ __forceinline__ void edge_accum(float4 raw, const __half2* xr2, const __half2* att2,
                                           float& lsum, float* acc, bool valid) {
    __half2* hp = (__half2*)&raw;
    const __half2 neg2 = __float2half2_rn(NEG);
    float p = 0.f;
    #pragma unroll
    for (int j = 0; j < 4; j++) {
        __half2 z = __hadd2(hp[j], xr2[j]);
        __half2 lz = pk_max(z, __hmul2(z, neg2));
#if __has_builtin(__builtin_amdgcn_fdot2)
        p = __builtin_amdgcn_fdot2(*(f16x2*)&lz, *(const f16x2*)&att2[j], p, false);
#else
        float2 lf = __half22float2(lz);
        float2 af = __half22float2(att2[j]);
        p = fmaf(lf.x, af.x, p);
        p = fmaf(lf.y, af.y, p);
#endif
    }
    p += __shfl_xor(p, 1, 64);
    p += __shfl_xor(p, 2, 64);
    p += __shfl_xor(p, 4, 64);
    p += __shfl_xor(p, 8, 64);
    float w = valid ? __expf(p) : 0.f;
    lsum += w;
    #pragma unroll
    for (int j = 0; j < 4; j++) {
        acc[2 * j]     = fmaf(__low2float(hp[j]),  w, acc[2 * j]);
        acc[2 * j + 1] = fmaf(__high2float(hp[j]), w, acc[2 * j + 1]);
    }
}

template <int LAYER>
__global__ __launch_bounds__(256) void gat_kernel(const __half* __restrict__ xl,
                                                  const float* __restrict__ xr,
                                                  const float* __restrict__ att,
                                                  const float* __restrict__ bias,
                                                  const int* __restrict__ row_ptr,
                                                  const int* __restrict__ srcs,
                                                  float* __restrict__ h_out,       // LAYER==1
                                                  const float* __restrict__ Wlin,  // LAYER==2
                                                  const float* __restrict__ blin,
                                                  float* __restrict__ out) {
    int dstn = blockIdx.x;
    int t = threadIdx.x;
    int slot = t >> 7;
    int c0 = (t & 127) * 8;

    __half2 xr2[4], att2[4];
    {
        float4 a0 = *(const float4*)(xr + (size_t)dstn * HC + c0);
        float4 a1 = *(const float4*)(xr + (size_t)dstn * HC + c0 + 4);
        xr2[0] = __floats2half2_rn(a0.x, a0.y);
        xr2[1] = __floats2half2_rn(a0.z, a0.w);
        xr2[2] = __floats2half2_rn(a1.x, a1.y);
        xr2[3] = __floats2half2_rn(a1.z, a1.w);
        float4 b0 = *(const float4*)(att + c0);
        float4 b1 = *(const float4*)(att + c0 + 4);
        att2[0] = __floats2half2_rn(b0.x, b0.y);
        att2[1] = __floats2half2_rn(b0.z, b0.w);
        att2[2] = __floats2half2_rn(b1.x, b1.y);
        att2[3] = __floats2half2_rn(b1.z, b1.w);
    }

    float acc[8];
    #pragma unroll
    for (int j = 0; j < 8; j++) acc[j] = 0.f;
    float lsum = 0.f;

    int e0 = row_ptr[dstn], e1 = row_ptr[dstn + 1];
    int e = e0;
    for (; e + 16 <= e1; e += 16) {
        int s[8];
        #pragma unroll
        for (int i = 0; i < 8; i++) s[i] = srcs[e + slot + 2 * i];
        float4 raw[8];
        #pragma unroll
        for (int i = 0; i < 8; i++) raw[i] = *(const float4*)(xl + (size_t)s[i] * HC + c0);
        #pragma unroll
        for (int i = 0; i < 8; i++) edge_accum(raw[i], xr2, att2, lsum, acc, true);
    }
    for (; e + 4 <= e1; e += 4) {
        int s[2];
        #pragma unroll
        for (int i = 0; i < 2; i++) s[i] = srcs[e + slot + 2 * i];
        float4 raw[2];
        #pragma unroll
        for (int i = 0; i < 2; i++) raw[i] = *(const float4*)(xl + (size_t)s[i] * HC + c0);
        #pragma unroll
        for (int i = 0; i < 2; i++) edge_accum(raw[i], xr2, att2, lsum, acc, true);
    }
    for (; e < e1; e += 2) {
        int ee = e + slot;
        bool valid = ee < e1;
        int s = srcs[valid ? ee : e];
        float4 raw = *(const float4*)(xl + (size_t)s * HC + c0);
        edge_accum(raw, xr2, att2, lsum, acc, valid);
    }

    __shared__ float part[2][HC];
    __shared__ float lpart[2][8];
    __shared__ float hrow[CH];
    #pragma unroll
    for (int j = 0; j < 8; j++) part[slot][c0 + j] = acc[j];
    if ((t & 15) == 0) lpart[slot][c0 >> 7] = lsum;
    __syncthreads();

    if (t < 128) {
        int head = t >> 4;
        float l = lpart[0][head] + lpart[1][head];
        float inv = 1.f / (l + 1e-16f);
        #pragma unroll
        for (int j = 0; j < 8; j++) {
            int c = t * 8 + j;
            part[0][c] = (part[0][c] + part[1][c]) * inv;
        }
    }
    __syncthreads();
    if (t < 128) {
        float ssum = 0.f;
        #pragma unroll
        for (int h = 0; h < 8; h++) ssum += part[0][h * 128 + t];
        float val = fmaxf(ssum * 0.125f + bias[t], 0.f);
        if (LAYER == 1) h_out[(size_t)dstn * CH + t] = val;
        else hrow[t] = val;
    }
    if (LAYER == 2) {
        __syncthreads();
        if (t < 64) {
            int j = t & 7, p8 = t >> 3;
            float v = 0.f;
            #pragma unroll
            for (int kk = 0; kk < 16; kk++) {
                int k = p8 * 16 + kk;
                v = fmaf(hrow[k], Wlin[k * 8 + j], v);
            }
            v += __shfl_xor(v, 8, 64);
            v += __shfl_xor(v, 16, 64);
            v += __shfl_xor(v, 32, 64);
            if (t < 8) out[(size_t)dstn * 8 + t] = v + blin[t];
        }
    }
}

extern "C" void kernel_launch(void* const* d_in, const int* in_sizes, int n_in,
                              void* d_out, int out_size, void* d_ws, size_t ws_size,
                              hipStream_t stream) {
    const float* x    = (const float*)d_in[0];
    const int*   ei   = (const int*)d_in[1];     // [2, E]
    const float* Wl1  = (const float*)d_in[2];
    const float* bl1  = (const float*)d_in[3];
    const float* Wr1  = (const float*)d_in[4];
    const float* br1  = (const float*)d_in[5];
    const float* att1 = (const float*)d_in[6];
    const float* b1   = (const float*)d_in[7];
    const float* Wl2  = (const float*)d_in[8];
    const float* bl2  = (const float*)d_in[9];
    const float* Wr2  = (const float*)d_in[10];
    const float* br2  = (const float*)d_in[11];
    const float* att2 = (const float*)d_in[12];
    const float* b2   = (const float*)d_in[13];
    const float* Wlin = (const float*)d_in[14];
    const float* blin = (const float*)d_in[15];
    float* out = (float*)d_out;

    const int* esrc = ei;
    const int* edst = ei + N_EDGES;

    // workspace layout (all chunks 16B-aligned)
    char* p = (char*)d_ws;
    __half* xlh = (__half*)p;                  p += (size_t)N_NODES * HC * sizeof(__half);
    float*  xr  = (float*)p;                   p += (size_t)N_NODES * HC * sizeof(float);
    float*  h1  = (float*)p;                   p += (size_t)N_NODES * CH * sizeof(float);
    _Float16* w1l = (_Float16*)p;              p += 1024 * 32 * sizeof(_Float16);
    _Float16* w1r = (_Float16*)p;              p += 1024 * 32 * sizeof(_Float16);
    _Float16* w2l = (_Float16*)p;              p += 1024 * 128 * sizeof(_Float16);
    _Float16* w2r = (_Float16*)p;              p += 1024 * 128 * sizeof(_Float16);
    int* deg     = (int*)p;
    int* row_ptr = deg + N_NODES;              // N+1
    int* cursor  = row_ptr + N_NODES + 16;
    int* srcs    = cursor + N_NODES;           // N_TOT

    (void)hipMemsetAsync(deg, 0, N_NODES * sizeof(int), stream);
    hist_kernel<<<(N_EDGES + 255) / 256, 256, 0, stream>>>(edst, deg);
    scan_kernel<<<1, 1024, 0, stream>>>(deg, row_ptr, cursor);
    scatter_kernel<<<(N_TOT + 255) / 256, 256, 0, stream>>>(esrc, edst, cursor, srcs);
    convert_w<<<1280, 256, 0, stream>>>(Wl1, Wr1, Wl2, Wr2, w1l, w1r, w2l, w2r);

    dim3 ggrid((N_NODES + 63) / 64, 8);
    gemm_mfma<32, 16><<<ggrid, 256, 0, stream>>>(x, w1l, bl1, w1r, br1,
                                                 (_Float16*)xlh, xr, N_NODES, N_NODES);
    gat_kernel<1><<<N_NODES, 256, 0, stream>>>(xlh, xr, att1, b1, row_ptr, srcs,
                                               h1, nullptr, nullptr, nullptr);
    gemm_mfma<128, 128><<<ggrid, 256, 0, stream>>>(h1, w2l, bl2, w2r, br2,
                                                   (_Float16*)xlh, xr, N_NODES, NAG);
    gat_kernel<2><<<NAG, 256, 0, stream>>>(xlh, xr, att2, b2, row_ptr, srcs,
                                           nullptr, Wlin, blin, out);
}